// Round 4
// baseline (3876.391 us; speedup 1.0000x reference)
//
#include <hip/hip_runtime.h>
#include <hip/hip_bf16.h>

#define HID 300

// ---------------------------------------------------------------------------
// helpers
// ---------------------------------------------------------------------------
__device__ __forceinline__ float bf_lo(unsigned u) { return __uint_as_float(u << 16); }
__device__ __forceinline__ float bf_hi(unsigned u) { return __uint_as_float(u & 0xffff0000u); }
__device__ __forceinline__ float bf1(unsigned short v) { return __uint_as_float((unsigned)v << 16); }

__device__ __forceinline__ void atomic_pk_add_bf16(void* addr, unsigned data) {
    asm volatile("global_atomic_pk_add_bf16 %0, %1, off" :: "v"(addr), "v"(data) : "memory");
}

// ---------------------------------------------------------------------------
__global__ __launch_bounds__(256) void fill_f32(float* __restrict__ p, int n, float v)
{
    int i = blockIdx.x * blockDim.x + threadIdx.x;
    int stride = gridDim.x * blockDim.x;
    for (; i < n; i += stride) p[i] = v;
}

__global__ __launch_bounds__(256) void zero_b16(float4* __restrict__ p, size_t n4)
{
    size_t i = (size_t)blockIdx.x * blockDim.x + threadIdx.x;
    size_t stride = (size_t)gridDim.x * blockDim.x;
    const float4 z = {0.f, 0.f, 0.f, 0.f};
    for (; i < n4; i += stride) p[i] = z;
}

// ---------------------------------------------------------------------------
// Generic GEMM: C = act( [A1 | A2] @ B^T + bias )
// A1/A2 fp32 or bf16 (runtime flags). B fp32 row-major [N][ldb].
// Optional epilogue: atomicAdd into mol[molBatch[row]] (fused segment pool).
// BM=BN=64, BK=16, 256 threads, 4x4 per thread.
// ---------------------------------------------------------------------------
template <bool BF16_OUT>
__global__ __launch_bounds__(256) void gemm_f32(
    const void* __restrict__ A1, int K1, int a1_bf16,
    const void* __restrict__ A2, int K2, int a2_bf16,
    const float* __restrict__ B, int ldb,
    const float* __restrict__ bias,
    void* __restrict__ Cv,
    int M, int N, int do_relu,
    const int* __restrict__ molBatch, int molRows)
{
    const int Kt = K1 + K2;
    __shared__ float As[16][68];
    __shared__ float Bs[16][68];
    const int bm = blockIdx.x * 64;
    const int bn = blockIdx.y * 64;
    const int tid = threadIdx.x;
    const int tm = (tid >> 4) << 2;
    const int tn = (tid & 15) << 2;
    float acc[4][4] = {{0.f,0.f,0.f,0.f},{0.f,0.f,0.f,0.f},
                       {0.f,0.f,0.f,0.f},{0.f,0.f,0.f,0.f}};

    for (int k0 = 0; k0 < Kt; k0 += 16) {
#pragma unroll
        for (int i = 0; i < 4; ++i) {
            int idx = tid + i * 256;
            int row = idx >> 4, col = idx & 15;
            int gm = bm + row, gk = k0 + col;
            float v = 0.f;
            if (gm < M && gk < Kt) {
                if (gk < K1)
                    v = a1_bf16 ? bf1(((const unsigned short*)A1)[(size_t)gm * K1 + gk])
                                : ((const float*)A1)[(size_t)gm * K1 + gk];
                else
                    v = a2_bf16 ? bf1(((const unsigned short*)A2)[(size_t)gm * K2 + (gk - K1)])
                                : ((const float*)A2)[(size_t)gm * K2 + (gk - K1)];
            }
            As[col][row] = v;
        }
#pragma unroll
        for (int i = 0; i < 4; ++i) {
            int idx = tid + i * 256;
            int row = idx >> 4, col = idx & 15;
            int gn = bn + row, gk = k0 + col;
            float v = 0.f;
            if (gn < N && gk < Kt) v = B[(size_t)gn * ldb + gk];
            Bs[col][row] = v;
        }
        __syncthreads();
#pragma unroll
        for (int kk = 0; kk < 16; ++kk) {
            const float4 a4 = *(const float4*)&As[kk][tm];
            const float4 b4 = *(const float4*)&Bs[kk][tn];
            const float av[4] = {a4.x, a4.y, a4.z, a4.w};
            const float bv[4] = {b4.x, b4.y, b4.z, b4.w};
#pragma unroll
            for (int i = 0; i < 4; ++i)
#pragma unroll
                for (int j = 0; j < 4; ++j)
                    acc[i][j] += av[i] * bv[j];
        }
        __syncthreads();
    }

#pragma unroll
    for (int i = 0; i < 4; ++i) {
        int gm = bm + tm + i;
        if (gm >= M) continue;
#pragma unroll
        for (int j = 0; j < 4; ++j) {
            int gn = bn + tn + j;
            if (gn >= N) continue;
            float v = acc[i][j];
            if (bias) v += bias[gn];
            if (do_relu) v = fmaxf(v, 0.f);
            if (molBatch) {
                int mb = molBatch[gm];
                mb = ((unsigned)mb < (unsigned)molRows) ? mb : 0;
                atomicAdd(&((float*)Cv)[(size_t)mb * N + gn], v);
            } else if (BF16_OUT) {
                ((__hip_bfloat16*)Cv)[(size_t)gm * N + gn] = __float2bfloat16(v);
            } else {
                ((float*)Cv)[(size_t)gm * N + gn] = v;
            }
        }
    }
}

// ---------------------------------------------------------------------------
// edge_pass: one block per edge (grid-stride). thread p = channel pair 2p,2p+1.
//   m = relu(xa[src] + ea @ Wi_bond^T); [relu(+hn0[src])]; [relu(+hn1[src])]
//   accumulate into out[tgt]: fp32 atomics or packed-bf16 atomics.
// src/tgt/ea loads are block-uniform -> scalarized by compiler.
// ---------------------------------------------------------------------------
__global__ __launch_bounds__(192) void edge_pass(
    const unsigned* __restrict__ xa,    // [N,150] bf16-pairs
    const unsigned* __restrict__ hn0,   // or null
    const unsigned* __restrict__ hn1,   // or null
    const int* __restrict__ src,
    const int* __restrict__ tgt,
    const float* __restrict__ ea,       // [E,14]
    const float* __restrict__ Wi,       // [300,147]
    void* __restrict__ out,             // [N,300] fp32 or bf16, pre-zeroed
    int out_bf16, int E, int N)
{
    const int p = threadIdx.x;
    if (p >= HID / 2) return;
    float w0[14], w1[14];
#pragma unroll
    for (int k = 0; k < 14; ++k) {
        w0[k] = Wi[(2 * p) * 147 + 133 + k];
        w1[k] = Wi[(2 * p + 1) * 147 + 133 + k];
    }

    for (int e = blockIdx.x; e < E; e += gridDim.x) {
        int s = src[e];
        int t = tgt[e];
        s = ((unsigned)s < (unsigned)N) ? s : 0;
        t = ((unsigned)t < (unsigned)N) ? t : 0;
        const size_t srow = (size_t)s * (HID / 2) + p;
        unsigned ua = xa[srow];
        float a0 = bf_lo(ua), a1 = bf_hi(ua);
#pragma unroll
        for (int k = 0; k < 14; ++k) {
            float ev = ea[(size_t)e * 14 + k];
            a0 += ev * w0[k];
            a1 += ev * w1[k];
        }
        a0 = fmaxf(a0, 0.f); a1 = fmaxf(a1, 0.f);
        if (hn0) {
            unsigned u = hn0[srow];
            a0 = fmaxf(a0 + bf_lo(u), 0.f);
            a1 = fmaxf(a1 + bf_hi(u), 0.f);
        }
        if (hn1) {
            unsigned u = hn1[srow];
            a0 = fmaxf(a0 + bf_lo(u), 0.f);
            a1 = fmaxf(a1 + bf_hi(u), 0.f);
        }
        if (out_bf16) {
            union { __hip_bfloat16 h[2]; unsigned u; } pk;
            pk.h[0] = __float2bfloat16(a0);
            pk.h[1] = __float2bfloat16(a1);
            atomic_pk_add_bf16((char*)out + ((size_t)t * HID + 2 * p) * 2, pk.u);
        } else {
            float* o = (float*)out + (size_t)t * HID + 2 * p;
            atomicAdd(o, a0);
            atomicAdd(o + 1, a1);
        }
    }
}

// ---------------------------------------------------------------------------
__global__ __launch_bounds__(64) void ffn2_k(
    const float* __restrict__ h1, const float* __restrict__ w2,
    const float* __restrict__ b2, float* __restrict__ out, int B)
{
    const int b = blockIdx.x;
    float s = 0.f;
    for (int k = threadIdx.x; k < HID; k += 64)
        s += h1[(size_t)b * HID + k] * w2[k];
#pragma unroll
    for (int off = 32; off > 0; off >>= 1) s += __shfl_down(s, off);
    if (threadIdx.x == 0) out[b] = s + b2[0];
}

// ---------------------------------------------------------------------------
extern "C" void kernel_launch(void* const* d_in, const int* in_sizes, int n_in,
                              void* d_out, int out_size, void* d_ws, size_t ws_size,
                              hipStream_t stream)
{
    float* outp = (float*)d_out;
    const int fillBlocks = (out_size + 255) / 256;

    if (n_in < 12) {
        fill_f32<<<fillBlocks, 256, 0, stream>>>(outp, out_size, 2.0e6f + n_in);
        return;
    }

    const int N = in_sizes[0] / 133;   // atoms
    const int E = in_sizes[1] / 2;     // edges
    const int B = out_size;            // molecules

    const long long expect[12] = {
        (long long)N * 133, (long long)E * 2, (long long)E * 14, N,
        300LL * 147, 300LL * 300, 300LL * 433, 300,
        300LL * 300, 300, 300, 1 };
    for (int i = 0; i < 12; ++i) {
        if ((long long)in_sizes[i] != expect[i]) {
            fill_f32<<<fillBlocks, 256, 0, stream>>>(outp, out_size,
                                                     3.0e6f + 1.0e4f * i);
            return;
        }
    }

    // ---- workspace layout (bytes) -----------------------------------------
    // [0,        60e6)  xa   bf16 [N,300]
    // [60e6,    120e6)  nei_bf bf16 [N,300]  (pass 2/3 accumulator)
    // [120e6,   180e6)  hn1  bf16 [N,300]
    // [180e6,   240e6)  hn0  bf16 [N,300]
    // [60e6,    180e6)  neiF fp32 [N,300]   (pass 1 only; dead before hn1/nei_bf)
    // [240e6,   ...  )  mol fp32 [B,300], h1 fp32 [B,300]
    char* base = (char*)d_ws;
    const size_t atomBF  = (size_t)N * HID * sizeof(__hip_bfloat16);  // 60e6
    const size_t molBytes = (size_t)B * HID * sizeof(float);
    const size_t need = 4 * atomBF + 2 * molBytes;

    if (ws_size < need) {
        fill_f32<<<fillBlocks, 256, 0, stream>>>(outp, out_size,
                                                 (float)(ws_size >> 20));
        return;
    }

    const float* x     = (const float*)d_in[0];
    const int*   ei    = (const int*)d_in[1];
    const float* ea    = (const float*)d_in[2];
    const int*   batch = (const int*)d_in[3];
    const float* W_i   = (const float*)d_in[4];
    const float* W_h   = (const float*)d_in[5];
    const float* W_o   = (const float*)d_in[6];
    const float* W_ob  = (const float*)d_in[7];
    const float* f1w   = (const float*)d_in[8];
    const float* f1b   = (const float*)d_in[9];
    const float* f2w   = (const float*)d_in[10];
    const float* f2b   = (const float*)d_in[11];
    const int* src = ei;
    const int* tgt = ei + E;

    __hip_bfloat16* xa  = (__hip_bfloat16*)(base);
    __hip_bfloat16* nei = (__hip_bfloat16*)(base + atomBF);
    __hip_bfloat16* hn1 = (__hip_bfloat16*)(base + 2 * atomBF);
    __hip_bfloat16* hn0 = (__hip_bfloat16*)(base + 3 * atomBF);
    float*          neiF = (float*)(base + atomBF);          // overlays nei+hn1
    float*          mol  = (float*)(base + 4 * atomBF);
    float*          h1   = mol + (size_t)B * HID;

    const unsigned* xa_u  = (const unsigned*)xa;
    const unsigned* hn0_u = (const unsigned*)hn0;
    const unsigned* hn1_u = (const unsigned*)hn1;

    const dim3 gAtom((N + 63) / 64, (HID + 63) / 64);
    const dim3 gMol((B + 63) / 64, (HID + 63) / 64);
    const int EDGE_BLOCKS = 16384;
    const int ZERO_BLOCKS = 2048;
    const size_t neiF4  = (size_t)N * HID * 4 / 16;   // fp32 region in float4s
    const size_t neiB4  = (size_t)N * HID * 2 / 16;   // bf16 region in float4s
    const size_t mol4   = molBytes / 16;

    // 1. xa = x @ W_i[:, :133]^T   (bf16, no relu)
    gemm_f32<true><<<gAtom, 256, 0, stream>>>(x, 133, 0, nullptr, 0, 0,
        W_i, 147, nullptr, xa, N, HID, 0, nullptr, 0);
    // 2. nei0 = segsum(m0)  (fp32 accumulate)
    zero_b16<<<ZERO_BLOCKS, 256, 0, stream>>>((float4*)neiF, neiF4);
    edge_pass<<<EDGE_BLOCKS, 192, 0, stream>>>(xa_u, nullptr, nullptr, src, tgt,
        ea, W_i, neiF, 0, E, N);
    // 3. hn0 = nei0 @ W_h^T  (bf16)
    gemm_f32<true><<<gAtom, 256, 0, stream>>>(neiF, HID, 0, nullptr, 0, 0,
        W_h, HID, nullptr, hn0, N, HID, 0, nullptr, 0);
    // 4. nei1 = segsum(m1)  (bf16 pk-atomic accumulate)
    zero_b16<<<ZERO_BLOCKS, 256, 0, stream>>>((float4*)nei, neiB4);
    edge_pass<<<EDGE_BLOCKS, 192, 0, stream>>>(xa_u, hn0_u, nullptr, src, tgt,
        ea, W_i, nei, 1, E, N);
    // 5. hn1 = nei1 @ W_h^T  (bf16)
    gemm_f32<true><<<gAtom, 256, 0, stream>>>(nei, HID, 1, nullptr, 0, 0,
        W_h, HID, nullptr, hn1, N, HID, 0, nullptr, 0);
    // 6. atom_msg = segsum(m2)  (bf16)
    zero_b16<<<ZERO_BLOCKS, 256, 0, stream>>>((float4*)nei, neiB4);
    edge_pass<<<EDGE_BLOCKS, 192, 0, stream>>>(xa_u, hn0_u, hn1_u, src, tgt,
        ea, W_i, nei, 1, E, N);
    // 7. mol[b] = sum_atoms relu([x | msg] @ W_o^T + b)  (fused pool epilogue)
    zero_b16<<<ZERO_BLOCKS, 256, 0, stream>>>((float4*)mol, mol4);
    gemm_f32<false><<<gAtom, 256, 0, stream>>>(x, 133, 0, nei, HID, 1,
        W_o, 433, W_ob, mol, N, HID, 1, batch, B);
    // 8. h1 = relu(mol @ ffn1^T + b1)
    gemm_f32<false><<<gMol, 256, 0, stream>>>(mol, HID, 0, nullptr, 0, 0,
        f1w, HID, f1b, h1, B, HID, 1, nullptr, 0);
    // 9. out = h1 @ ffn2^T + b2
    ffn2_k<<<B, 64, 0, stream>>>(h1, f2w, f2b, outp, B);
}

// Round 5
// 1955.102 us; speedup vs baseline: 1.9827x; 1.9827x over previous
//
#include <hip/hip_runtime.h>
#include <hip/hip_bf16.h>
#include <hip/hip_fp16.h>

#define HID 300

typedef _Float16 f16;
typedef f16  f16x4 __attribute__((ext_vector_type(4)));
typedef float f32x4 __attribute__((ext_vector_type(4)));

// ---------------------------------------------------------------------------
// helpers
// ---------------------------------------------------------------------------
__device__ __forceinline__ float f16lo(unsigned u) {
    union { unsigned short s; f16 h; } c; c.s = (unsigned short)(u & 0xffffu);
    return (float)c.h;
}
__device__ __forceinline__ float f16hi(unsigned u) {
    union { unsigned short s; f16 h; } c; c.s = (unsigned short)(u >> 16);
    return (float)c.h;
}
__device__ __forceinline__ unsigned pk16(float a, float b) {
    union { f16 h[2]; unsigned u; } c; c.h[0] = (f16)a; c.h[1] = (f16)b;
    return c.u;
}
__device__ __forceinline__ void atomic_pk_add_f16(void* addr, unsigned data) {
    asm volatile("global_atomic_pk_add_f16 %0, %1, off" :: "v"(addr), "v"(data) : "memory");
}

// ---------------------------------------------------------------------------
__global__ __launch_bounds__(256) void fill_f32(float* __restrict__ p, int n, float v)
{
    int i = blockIdx.x * blockDim.x + threadIdx.x;
    int stride = gridDim.x * blockDim.x;
    for (; i < n; i += stride) p[i] = v;
}

__global__ __launch_bounds__(256) void zero16(float4* __restrict__ p, size_t n4)
{
    size_t i = (size_t)blockIdx.x * blockDim.x + threadIdx.x;
    size_t stride = (size_t)gridDim.x * blockDim.x;
    const float4 z = {0.f, 0.f, 0.f, 0.f};
    for (; i < n4; i += stride) p[i] = z;
}

// dst [rows][kpad] f16, zero-padded; src fp32 row-major stride ldsrc, kuse cols
__global__ __launch_bounds__(256) void cvt_pad_f16(
    f16* __restrict__ dst, const float* __restrict__ src,
    int rows, int ldsrc, int kuse, int kpad)
{
    int i = blockIdx.x * 256 + threadIdx.x;
    const int total = rows * kpad;
    const int st = gridDim.x * 256;
    for (; i < total; i += st) {
        int r = i / kpad, k = i - r * kpad;
        dst[i] = (k < kuse) ? (f16)src[(size_t)r * ldsrc + k] : (f16)0.f;
    }
}

// ---------------------------------------------------------------------------
// MFMA GEMM: C = act( [A1 | A2] @ Wf16^T + bias ),  N fixed = 300 (tiles 320)
// A segments fp32 or f16 ([M][K] row-major). W: f16 [300][kpad] zero-padded.
// Block: 256 thr = 4 waves, BM=64; wave w computes rows 0..63 x cols 80w..80w+80
// via 4x5 tiles of v_mfma_f32_16x16x16_f16. A is read ONCE from global.
// cmode: 0 = f32 store, 1 = f16 store, 2 = atomicAdd into mol[batch[row]] (f32)
// ---------------------------------------------------------------------------
__global__ __launch_bounds__(256) void gemm_mfma(
    const void* __restrict__ A1, int K1, int a1f16,
    const void* __restrict__ A2, int K2, int a2f16,
    const f16* __restrict__ W, int kpad,
    const float* __restrict__ bias,
    void* __restrict__ Cv, int cmode,
    int M, int do_relu,
    const int* __restrict__ molBatch, int molRows)
{
    const int Kt = K1 + K2;
    __shared__ f16 As[64][20];     // stride 20 halves (40 B): conflict-free
    __shared__ f16 Ws[320][20];
    const int tid  = threadIdx.x;
    const int bm   = blockIdx.x * 64;
    const int lane = tid & 63;
    const int wv   = tid >> 6;
    const int lm   = lane & 15;
    const int lk   = (lane >> 4) << 2;

    f32x4 acc[4][5];
#pragma unroll
    for (int r = 0; r < 4; ++r)
#pragma unroll
        for (int c = 0; c < 5; ++c) acc[r][c] = (f32x4){0.f, 0.f, 0.f, 0.f};

    const int arow = tid >> 2;             // A staging: row 0..63
    const int akg  = (tid & 3) << 2;       // k-subgroup 0/4/8/12
    const int nsteps = kpad >> 4;

    for (int s = 0; s < nsteps; ++s) {
        const int k0 = s << 4;
        // ---- stage A tile (64x16) ----
        {
            const int gm  = bm + arow;
            const int gk0 = k0 + akg;
            f16x4 v = (f16x4){0, 0, 0, 0};
            if (gm < M) {
                if (gk0 + 3 < K1) {
                    if (a1f16) v = *(const f16x4*)((const f16*)A1 + (size_t)gm * K1 + gk0);
                    else {
                        const float* p = (const float*)A1 + (size_t)gm * K1 + gk0;
                        v[0] = (f16)p[0]; v[1] = (f16)p[1];
                        v[2] = (f16)p[2]; v[3] = (f16)p[3];
                    }
                } else if (gk0 >= K1 && gk0 + 3 < Kt) {
                    const int g2 = gk0 - K1;
                    if (a2f16) v = *(const f16x4*)((const f16*)A2 + (size_t)gm * K2 + g2);
                    else {
                        const float* p = (const float*)A2 + (size_t)gm * K2 + g2;
                        v[0] = (f16)p[0]; v[1] = (f16)p[1];
                        v[2] = (f16)p[2]; v[3] = (f16)p[3];
                    }
                } else {
#pragma unroll
                    for (int j = 0; j < 4; ++j) {
                        const int gk = gk0 + j;
                        float f = 0.f;
                        if (gk < K1)
                            f = a1f16 ? (float)((const f16*)A1)[(size_t)gm * K1 + gk]
                                      : ((const float*)A1)[(size_t)gm * K1 + gk];
                        else if (gk < Kt) {
                            const int g2 = gk - K1;
                            f = a2f16 ? (float)((const f16*)A2)[(size_t)gm * K2 + g2]
                                      : ((const float*)A2)[(size_t)gm * K2 + g2];
                        }
                        v[j] = (f16)f;
                    }
                }
            }
            *(f16x4*)&As[arow][akg] = v;
        }
        // ---- stage W tile (320x16); W padded so loads are unguarded ----
#pragma unroll
        for (int it = 0; it < 5; ++it) {
            const int idx = tid + (it << 8);
            const int wr  = idx >> 2;
            const int kg  = (idx & 3) << 2;
            f16x4 v = (f16x4){0, 0, 0, 0};
            if (wr < HID)
                v = *(const f16x4*)(W + (size_t)wr * kpad + k0 + kg);
            *(f16x4*)&Ws[wr][kg] = v;
        }
        __syncthreads();
        // ---- fragments + 20 MFMA ----
        f16x4 af[4], bf[5];
#pragma unroll
        for (int r = 0; r < 4; ++r)
            af[r] = *(const f16x4*)&As[(r << 4) + lm][lk];
#pragma unroll
        for (int c = 0; c < 5; ++c)
            bf[c] = *(const f16x4*)&Ws[wv * 80 + (c << 4) + lm][lk];
#pragma unroll
        for (int r = 0; r < 4; ++r)
#pragma unroll
            for (int c = 0; c < 5; ++c)
                acc[r][c] = __builtin_amdgcn_mfma_f32_16x16x16f16(
                    af[r], bf[c], acc[r][c], 0, 0, 0);
        __syncthreads();
    }

    // ---- epilogue: C/D frag = (col = lane&15, row = 4*(lane>>4)+i) ----
#pragma unroll
    for (int r = 0; r < 4; ++r) {
        const int gm0 = bm + (r << 4) + ((lane >> 4) << 2);
#pragma unroll
        for (int c = 0; c < 5; ++c) {
            const int n = wv * 80 + (c << 4) + lm;
            if (n >= HID) continue;
#pragma unroll
            for (int i = 0; i < 4; ++i) {
                const int gm = gm0 + i;
                if (gm >= M) continue;
                float v = acc[r][c][i];
                if (bias) v += bias[n];
                if (do_relu) v = fmaxf(v, 0.f);
                if (cmode == 2) {
                    int mb = molBatch[gm];
                    mb = ((unsigned)mb < (unsigned)molRows) ? mb : 0;
                    atomicAdd(&((float*)Cv)[(size_t)mb * HID + n], v);
                } else if (cmode == 1) {
                    ((f16*)Cv)[(size_t)gm * HID + n] = (f16)v;
                } else {
                    ((float*)Cv)[(size_t)gm * HID + n] = v;
                }
            }
        }
    }
}

// ---------------------------------------------------------------------------
// edge_pass: recompute edge message on the fly, scatter pk-f16 atomics.
//   m0 = relu(xa[src] + ea @ Wi_bond^T); [relu(+hn0[src])]; [relu(+hn1[src])]
// one block per edge (grid-stride), thread p = channel pair (2p, 2p+1).
// ---------------------------------------------------------------------------
__global__ __launch_bounds__(192) void edge_pass(
    const unsigned* __restrict__ xa,    // [N,150] f16-pairs
    const unsigned* __restrict__ hn0,   // or null
    const unsigned* __restrict__ hn1,   // or null
    const int* __restrict__ src,
    const int* __restrict__ tgt,
    const float* __restrict__ ea,       // [E,14]
    const float* __restrict__ Wi,       // [300,147] fp32 (bond cols 133..146)
    unsigned* __restrict__ out,         // [N,150] f16-pairs, pre-zeroed
    int E, int N)
{
    const int p = threadIdx.x;
    if (p >= HID / 2) return;
    float w0[14], w1[14];
#pragma unroll
    for (int k = 0; k < 14; ++k) {
        w0[k] = Wi[(2 * p) * 147 + 133 + k];
        w1[k] = Wi[(2 * p + 1) * 147 + 133 + k];
    }

    for (int e = blockIdx.x; e < E; e += gridDim.x) {
        int s = src[e];
        int t = tgt[e];
        s = ((unsigned)s < (unsigned)N) ? s : 0;
        t = ((unsigned)t < (unsigned)N) ? t : 0;
        const size_t srow = (size_t)s * (HID / 2) + p;
        unsigned ua = xa[srow];
        float a0 = f16lo(ua), a1 = f16hi(ua);
#pragma unroll
        for (int k = 0; k < 14; ++k) {
            const float ev = ea[(size_t)e * 14 + k];
            a0 += ev * w0[k];
            a1 += ev * w1[k];
        }
        a0 = fmaxf(a0, 0.f); a1 = fmaxf(a1, 0.f);
        if (hn0) {
            unsigned u = hn0[srow];
            a0 = fmaxf(a0 + f16lo(u), 0.f);
            a1 = fmaxf(a1 + f16hi(u), 0.f);
        }
        if (hn1) {
            unsigned u = hn1[srow];
            a0 = fmaxf(a0 + f16lo(u), 0.f);
            a1 = fmaxf(a1 + f16hi(u), 0.f);
        }
        atomic_pk_add_f16(&out[(size_t)t * (HID / 2) + p], pk16(a0, a1));
    }
}

// ---------------------------------------------------------------------------
// small fp32 GEMM (kept for mol FFN1): C = relu(A @ B^T + bias)
// ---------------------------------------------------------------------------
__global__ __launch_bounds__(256) void gemm_f32s(
    const float* __restrict__ A, int K,
    const float* __restrict__ B, int ldb,
    const float* __restrict__ bias,
    float* __restrict__ C, int M, int N, int do_relu)
{
    __shared__ float As[16][68];
    __shared__ float Bs[16][68];
    const int bm = blockIdx.x * 64;
    const int bn = blockIdx.y * 64;
    const int tid = threadIdx.x;
    const int tm = (tid >> 4) << 2;
    const int tn = (tid & 15) << 2;
    float acc[4][4] = {{0.f,0.f,0.f,0.f},{0.f,0.f,0.f,0.f},
                       {0.f,0.f,0.f,0.f},{0.f,0.f,0.f,0.f}};

    for (int k0 = 0; k0 < K; k0 += 16) {
#pragma unroll
        for (int i = 0; i < 4; ++i) {
            int idx = tid + i * 256;
            int row = idx >> 4, col = idx & 15;
            int gm = bm + row, gk = k0 + col;
            As[col][row] = (gm < M && gk < K) ? A[(size_t)gm * K + gk] : 0.f;
        }
#pragma unroll
        for (int i = 0; i < 4; ++i) {
            int idx = tid + i * 256;
            int row = idx >> 4, col = idx & 15;
            int gn = bn + row, gk = k0 + col;
            Bs[col][row] = (gn < N && gk < K) ? B[(size_t)gn * ldb + gk] : 0.f;
        }
        __syncthreads();
#pragma unroll
        for (int kk = 0; kk < 16; ++kk) {
            const float4 a4 = *(const float4*)&As[kk][tm];
            const float4 b4 = *(const float4*)&Bs[kk][tn];
            const float av[4] = {a4.x, a4.y, a4.z, a4.w};
            const float bv[4] = {b4.x, b4.y, b4.z, b4.w};
#pragma unroll
            for (int i = 0; i < 4; ++i)
#pragma unroll
                for (int j = 0; j < 4; ++j)
                    acc[i][j] += av[i] * bv[j];
        }
        __syncthreads();
    }
#pragma unroll
    for (int i = 0; i < 4; ++i) {
        int gm = bm + tm + i;
        if (gm >= M) continue;
#pragma unroll
        for (int j = 0; j < 4; ++j) {
            int gn = bn + tn + j;
            if (gn >= N) continue;
            float v = acc[i][j];
            if (bias) v += bias[gn];
            if (do_relu) v = fmaxf(v, 0.f);
            C[(size_t)gm * N + gn] = v;
        }
    }
}

// ---------------------------------------------------------------------------
__global__ __launch_bounds__(64) void ffn2_k(
    const float* __restrict__ h1, const float* __restrict__ w2,
    const float* __restrict__ b2, float* __restrict__ out, int B)
{
    const int b = blockIdx.x;
    float s = 0.f;
    for (int k = threadIdx.x; k < HID; k += 64)
        s += h1[(size_t)b * HID + k] * w2[k];
#pragma unroll
    for (int off = 32; off > 0; off >>= 1) s += __shfl_down(s, off);
    if (threadIdx.x == 0) out[b] = s + b2[0];
}

// ---------------------------------------------------------------------------
extern "C" void kernel_launch(void* const* d_in, const int* in_sizes, int n_in,
                              void* d_out, int out_size, void* d_ws, size_t ws_size,
                              hipStream_t stream)
{
    float* outp = (float*)d_out;
    const int fillBlocks = (out_size + 255) / 256;

    if (n_in < 12) {
        fill_f32<<<fillBlocks, 256, 0, stream>>>(outp, out_size, 2.0e6f + n_in);
        return;
    }

    const int N = in_sizes[0] / 133;   // atoms
    const int E = in_sizes[1] / 2;     // edges
    const int B = out_size;            // molecules

    const long long expect[12] = {
        (long long)N * 133, (long long)E * 2, (long long)E * 14, N,
        300LL * 147, 300LL * 300, 300LL * 433, 300,
        300LL * 300, 300, 300, 1 };
    for (int i = 0; i < 12; ++i) {
        if ((long long)in_sizes[i] != expect[i]) {
            fill_f32<<<fillBlocks, 256, 0, stream>>>(outp, out_size,
                                                     3.0e6f + 1.0e4f * i);
            return;
        }
    }

    // ---- workspace layout --------------------------------------------------
    // [0,60e6)    xa  f16 [N,300]
    // [60,120e6)  nei f16 [N,300]   (accumulator, reused all 3 passes)
    // [120,180e6) hn1 f16
    // [180,240e6) hn0 f16
    // [240e6...)  WiA16 [300][144], Wh16 [300][304], Wo16 [300][448],
    //             mol f32 [B,300], h1 f32 [B,300]
    char* base = (char*)d_ws;
    const size_t atomF16  = (size_t)N * HID * sizeof(f16);    // 60e6
    const size_t molBytes = (size_t)B * HID * sizeof(float);
    const size_t wiB = 300 * 144 * sizeof(f16);
    const size_t whB = 300 * 304 * sizeof(f16);
    const size_t woB = 300 * 448 * sizeof(f16);
    const size_t need = 4 * atomF16 + wiB + whB + woB + 2 * molBytes;

    if (ws_size < need) {
        fill_f32<<<fillBlocks, 256, 0, stream>>>(outp, out_size,
                                                 (float)(ws_size >> 20));
        return;
    }

    const float* x     = (const float*)d_in[0];
    const int*   ei    = (const int*)d_in[1];
    const float* ea    = (const float*)d_in[2];
    const int*   batch = (const int*)d_in[3];
    const float* W_i   = (const float*)d_in[4];
    const float* W_h   = (const float*)d_in[5];
    const float* W_o   = (const float*)d_in[6];
    const float* W_ob  = (const float*)d_in[7];
    const float* f1w   = (const float*)d_in[8];
    const float* f1b   = (const float*)d_in[9];
    const float* f2w   = (const float*)d_in[10];
    const float* f2b   = (const float*)d_in[11];
    const int* src = ei;
    const int* tgt = ei + E;

    f16* xa   = (f16*)(base);
    f16* nei  = (f16*)(base + atomF16);
    f16* hn1  = (f16*)(base + 2 * atomF16);
    f16* hn0  = (f16*)(base + 3 * atomF16);
    f16* WiA16 = (f16*)(base + 4 * atomF16);
    f16* Wh16  = (f16*)((char*)WiA16 + wiB);
    f16* Wo16  = (f16*)((char*)Wh16 + whB);
    float* mol = (float*)((char*)Wo16 + woB);
    float* h1  = mol + (size_t)B * HID;

    const unsigned* xa_u  = (const unsigned*)xa;
    const unsigned* hn0_u = (const unsigned*)hn0;
    const unsigned* hn1_u = (const unsigned*)hn1;
    unsigned*       nei_u = (unsigned*)nei;

    const int gAtom = (N + 63) / 64;               // 1563 blocks, full N=300
    const dim3 gMol((B + 63) / 64, (HID + 63) / 64);
    const int EDGE_BLOCKS = 16384;
    const int ZERO_BLOCKS = 2048;
    const size_t nei4 = atomF16 / 16;
    const size_t mol4 = molBytes / 16;

    // 0. weights -> padded f16
    cvt_pad_f16<<<64,  256, 0, stream>>>(WiA16, W_i, 300, 147, 133, 144);
    cvt_pad_f16<<<128, 256, 0, stream>>>(Wh16,  W_h, 300, 300, 300, 304);
    cvt_pad_f16<<<160, 256, 0, stream>>>(Wo16,  W_o, 300, 433, 433, 448);

    // 1. xa = x @ W_i[:, :133]^T  (f16 out, no relu)
    gemm_mfma<<<gAtom, 256, 0, stream>>>(x, 133, 0, nullptr, 0, 0,
        WiA16, 144, nullptr, xa, 1, N, 0, nullptr, 0);
    // 2. nei0 = segsum(m0)
    zero16<<<ZERO_BLOCKS, 256, 0, stream>>>((float4*)nei, nei4);
    edge_pass<<<EDGE_BLOCKS, 192, 0, stream>>>(xa_u, nullptr, nullptr, src, tgt,
        ea, W_i, nei_u, E, N);
    // 3. hn0 = nei0 @ W_h^T
    gemm_mfma<<<gAtom, 256, 0, stream>>>(nei, 300, 1, nullptr, 0, 0,
        Wh16, 304, nullptr, hn0, 1, N, 0, nullptr, 0);
    // 4. nei1 = segsum(m1)
    zero16<<<ZERO_BLOCKS, 256, 0, stream>>>((float4*)nei, nei4);
    edge_pass<<<EDGE_BLOCKS, 192, 0, stream>>>(xa_u, hn0_u, nullptr, src, tgt,
        ea, W_i, nei_u, E, N);
    // 5. hn1 = nei1 @ W_h^T
    gemm_mfma<<<gAtom, 256, 0, stream>>>(nei, 300, 1, nullptr, 0, 0,
        Wh16, 304, nullptr, hn1, 1, N, 0, nullptr, 0);
    // 6. atom_msg = segsum(m2)
    zero16<<<ZERO_BLOCKS, 256, 0, stream>>>((float4*)nei, nei4);
    edge_pass<<<EDGE_BLOCKS, 192, 0, stream>>>(xa_u, hn0_u, hn1_u, src, tgt,
        ea, W_i, nei_u, E, N);
    // 7. mol[b] = sum_atoms relu([x | msg] @ W_o^T + b)  (fused pool epilogue)
    zero16<<<ZERO_BLOCKS, 256, 0, stream>>>((float4*)mol, mol4);
    gemm_mfma<<<gAtom, 256, 0, stream>>>(x, 133, 0, nei, 300, 1,
        Wo16, 448, W_ob, mol, 2, N, 1, batch, B);
    // 8. h1 = relu(mol @ ffn1^T + b1)   (fp32 path for final precision)
    gemm_f32s<<<gMol, 256, 0, stream>>>(mol, HID, f1w, HID, f1b, h1, B, HID, 1);
    // 9. out = h1 @ ffn2^T + b2
    ffn2_k<<<B, 64, 0, stream>>>(h1, f2w, f2b, outp, B);
}

// Round 6
// 1318.254 us; speedup vs baseline: 2.9405x; 1.4831x over previous
//
#include <hip/hip_runtime.h>
#include <hip/hip_fp16.h>

#define HID  300
#define HIDP 320   // padded hidden

typedef _Float16 f16;
typedef f16  f16x4 __attribute__((ext_vector_type(4)));
typedef float f32x4 __attribute__((ext_vector_type(4)));

// ---------------------------------------------------------------------------
// helpers
// ---------------------------------------------------------------------------
__device__ __forceinline__ float f16lo(unsigned u) {
    union { unsigned short s; f16 h; } c; c.s = (unsigned short)(u & 0xffffu);
    return (float)c.h;
}
__device__ __forceinline__ float f16hi(unsigned u) {
    union { unsigned short s; f16 h; } c; c.s = (unsigned short)(u >> 16);
    return (float)c.h;
}
__device__ __forceinline__ unsigned pk16(float a, float b) {
    union { f16 h[2]; unsigned u; } c; c.h[0] = (f16)a; c.h[1] = (f16)b;
    return c.u;
}
__device__ __forceinline__ void atomic_pk_add_f16(void* addr, unsigned data) {
    asm volatile("global_atomic_pk_add_f16 %0, %1, off" :: "v"(addr), "v"(data) : "memory");
}

// ---------------------------------------------------------------------------
__global__ __launch_bounds__(256) void fill_f32(float* __restrict__ p, int n, float v)
{
    int i = blockIdx.x * blockDim.x + threadIdx.x;
    int stride = gridDim.x * blockDim.x;
    for (; i < n; i += stride) p[i] = v;
}

__global__ __launch_bounds__(256) void zero16(float4* __restrict__ p, size_t n4)
{
    size_t i = (size_t)blockIdx.x * blockDim.x + threadIdx.x;
    size_t stride = (size_t)gridDim.x * blockDim.x;
    const float4 z = {0.f, 0.f, 0.f, 0.f};
    for (; i < n4; i += stride) p[i] = z;
}

// dst [dstRows][kpad] f16 zero-padded; src fp32 [srcRows][ldsrc], kuse cols used
__global__ __launch_bounds__(256) void cvt_pad_f16(
    f16* __restrict__ dst, const float* __restrict__ src,
    int srcRows, int ldsrc, int kuse, int kpad, int dstRows)
{
    int i = blockIdx.x * 256 + threadIdx.x;
    const int total = dstRows * kpad;
    const int st = gridDim.x * 256;
    for (; i < total; i += st) {
        int r = i / kpad, k = i - r * kpad;
        dst[i] = (r < srcRows && k < kuse) ? (f16)src[(size_t)r * ldsrc + k]
                                           : (f16)0.f;
    }
}

// ---------------------------------------------------------------------------
// MFMA GEMM (two-phase): C = act( A1@W1^T + A2@W2^T + bias ), all N=320 cols.
// A fp32 (guarded, Kuse cols) or f16 (unguarded, row stride lda, padded).
// W f16 [320][kpad], fully zero-padded. C: f16 [M][320].
// Block: 512 thr = 8 waves (2 row-groups x 4 col-groups), BM=128, BK=16,
// double-buffered LDS, v_mfma_f32_16x16x16_f16, one barrier per K-step.
// ---------------------------------------------------------------------------
__global__ __launch_bounds__(512) void gemm_mfma(
    const void* __restrict__ A1, int lda1, int a1f16, int K1use,
    const f16* __restrict__ W1, int kpad1,
    const void* __restrict__ A2, int lda2, int a2f16, int K2use,
    const f16* __restrict__ W2, int kpad2,
    const float* __restrict__ bias,
    f16* __restrict__ C,
    int M, int do_relu)
{
    __shared__ f16 As[2][128][20];
    __shared__ f16 Ws[2][320][20];

    const int tid  = threadIdx.x;
    const int bm   = blockIdx.x * 128;
    const int lane = tid & 63;
    const int wv   = tid >> 6;          // 0..7
    const int wrow = (wv >> 2) * 64;    // 0 / 64
    const int wcol = (wv & 3) * 80;     // 0/80/160/240
    const int lm   = lane & 15;
    const int lk   = (lane >> 4) << 2;

    const int n1 = A1 ? (kpad1 >> 4) : 0;
    const int n2 = A2 ? (kpad2 >> 4) : 0;
    const int ntot = n1 + n2;

    f32x4 acc[4][5];
#pragma unroll
    for (int r = 0; r < 4; ++r)
#pragma unroll
        for (int c = 0; c < 5; ++c) acc[r][c] = (f32x4){0.f, 0.f, 0.f, 0.f};

    const int arow = tid >> 2;          // 0..127
    const int akg  = (tid & 3) << 2;    // 0/4/8/12

    auto stage = [&](int s, int b) {
        const void* A; int lda, af16, Kuse, kpad; const f16* W; int k0;
        if (s < n1) { A = A1; lda = lda1; af16 = a1f16; Kuse = K1use;
                      W = W1; kpad = kpad1; k0 = s << 4; }
        else        { A = A2; lda = lda2; af16 = a2f16; Kuse = K2use;
                      W = W2; kpad = kpad2; k0 = (s - n1) << 4; }
        // A tile 128x16
        const int gm = bm + arow;
        const int gk = k0 + akg;
        f16x4 va = (f16x4){0, 0, 0, 0};
        if (gm < M) {
            if (af16) {
                va = *(const f16x4*)((const f16*)A + (size_t)gm * lda + gk);
            } else {
                const float* p = (const float*)A + (size_t)gm * lda + gk;
#pragma unroll
                for (int j = 0; j < 4; ++j)
                    va[j] = (gk + j < Kuse) ? (f16)p[j] : (f16)0.f;
            }
        }
        *(f16x4*)&As[b][arow][akg] = va;
        // W tile 320x16 = 1280 f16x4 (unguarded: W fully padded)
#pragma unroll
        for (int it = 0; it < 3; ++it) {
            const int idx = tid + (it << 9);
            if (idx < 1280) {
                const int wr = idx >> 2, kg = (idx & 3) << 2;
                *(f16x4*)&Ws[b][wr][kg] =
                    *(const f16x4*)(W + (size_t)wr * kpad + k0 + kg);
            }
        }
    };

    auto compute = [&](int b) {
        f16x4 af[4], bf[5];
#pragma unroll
        for (int r = 0; r < 4; ++r)
            af[r] = *(const f16x4*)&As[b][wrow + (r << 4) + lm][lk];
#pragma unroll
        for (int c = 0; c < 5; ++c)
            bf[c] = *(const f16x4*)&Ws[b][wcol + (c << 4) + lm][lk];
#pragma unroll
        for (int r = 0; r < 4; ++r)
#pragma unroll
            for (int c = 0; c < 5; ++c)
                acc[r][c] = __builtin_amdgcn_mfma_f32_16x16x16f16(
                    af[r], bf[c], acc[r][c], 0, 0, 0);
    };

    int b = 0;
    stage(0, 0);
    for (int s = 0; s < ntot; ++s) {
        __syncthreads();                  // stage(s) LDS-visible
        if (s + 1 < ntot) stage(s + 1, b ^ 1);   // loads overlap MFMA
        compute(b);
        b ^= 1;
    }

    // epilogue: C/D frag col = lane&15, row = 4*(lane>>4)+i
#pragma unroll
    for (int r = 0; r < 4; ++r) {
        const int gm0 = bm + wrow + (r << 4) + ((lane >> 4) << 2);
#pragma unroll
        for (int c = 0; c < 5; ++c) {
            const int n = wcol + (c << 4) + lm;
            const float bi = bias ? ((n < HID) ? bias[n] : 0.f) : 0.f;
#pragma unroll
            for (int i = 0; i < 4; ++i) {
                const int gm = gm0 + i;
                if (gm >= M) continue;
                float v = acc[r][c][i] + bi;
                if (do_relu) v = fmaxf(v, 0.f);
                C[(size_t)gm * HIDP + n] = (f16)v;
            }
        }
    }
}

// ---------------------------------------------------------------------------
// edge_pass: recompute edge message on the fly, scatter pk-f16 atomics.
//   m0 = relu(xa[src] + ea @ Wi_bond^T); [relu(+hn0[src])]; [relu(+hn1[src])]
// one block per edge (grid-stride), thread p = channel pair (2p, 2p+1).
// ---------------------------------------------------------------------------
__global__ __launch_bounds__(192) void edge_pass(
    const unsigned* __restrict__ xa,    // [N,160] f16-pairs (padded)
    const unsigned* __restrict__ hn0,   // or null
    const unsigned* __restrict__ hn1,   // or null
    const int* __restrict__ src,
    const int* __restrict__ tgt,
    const float* __restrict__ ea,       // [E,14]
    const float* __restrict__ Wi,       // [300,147] fp32 (bond cols 133..146)
    unsigned* __restrict__ out,         // [N,160] f16-pairs, pre-zeroed
    int E, int N)
{
    const int p = threadIdx.x;
    if (p >= HID / 2) return;
    float w0[14], w1[14];
#pragma unroll
    for (int k = 0; k < 14; ++k) {
        w0[k] = Wi[(2 * p) * 147 + 133 + k];
        w1[k] = Wi[(2 * p + 1) * 147 + 133 + k];
    }

    const int ld = HIDP / 2;   // 160 pairs
    for (int e = blockIdx.x; e < E; e += gridDim.x) {
        int s = src[e];
        int t = tgt[e];
        s = ((unsigned)s < (unsigned)N) ? s : 0;
        t = ((unsigned)t < (unsigned)N) ? t : 0;
        const size_t srow = (size_t)s * ld + p;
        unsigned ua = xa[srow];
        float a0 = f16lo(ua), a1 = f16hi(ua);
#pragma unroll
        for (int k = 0; k < 14; ++k) {
            const float ev = ea[(size_t)e * 14 + k];
            a0 += ev * w0[k];
            a1 += ev * w1[k];
        }
        a0 = fmaxf(a0, 0.f); a1 = fmaxf(a1, 0.f);
        if (hn0) {
            unsigned u = hn0[srow];
            a0 = fmaxf(a0 + f16lo(u), 0.f);
            a1 = fmaxf(a1 + f16hi(u), 0.f);
        }
        if (hn1) {
            unsigned u = hn1[srow];
            a0 = fmaxf(a0 + f16lo(u), 0.f);
            a1 = fmaxf(a1 + f16hi(u), 0.f);
        }
        atomic_pk_add_f16(&out[(size_t)t * ld + p], pk16(a0, a1));
    }
}

// ---------------------------------------------------------------------------
// mol_pool: mol[b,:300] = sum of atom_h rows (f16, ld 320) with batch[a]==b
// ---------------------------------------------------------------------------
__global__ __launch_bounds__(256) void mol_pool(
    const f16* __restrict__ ah,       // [N,320] f16
    const int* __restrict__ batch,    // [N], sorted
    float* __restrict__ mol,          // [B,300]
    int N)
{
    const int b = blockIdx.x;
    int lo = 0, hi = N;
    while (lo < hi) { int mid = (lo + hi) >> 1; if (batch[mid] < b) lo = mid + 1; else hi = mid; }
    const int start = lo;
    hi = N;
    while (lo < hi) { int mid = (lo + hi) >> 1; if (batch[mid] < b + 1) lo = mid + 1; else hi = mid; }
    const int end = lo;

    for (int h = threadIdx.x; h < HID; h += 256) {
        float s = 0.f;
        for (int a = start; a < end; ++a) s += (float)ah[(size_t)a * HIDP + h];
        mol[(size_t)b * HID + h] = s;
    }
}

// ---------------------------------------------------------------------------
// small fp32 GEMM (mol FFN1): C = relu(A @ B^T + bias)
// ---------------------------------------------------------------------------
__global__ __launch_bounds__(256) void gemm_f32s(
    const float* __restrict__ A, int K,
    const float* __restrict__ B, int ldb,
    const float* __restrict__ bias,
    float* __restrict__ C, int M, int N, int do_relu)
{
    __shared__ float As[16][68];
    __shared__ float Bs[16][68];
    const int bm = blockIdx.x * 64;
    const int bn = blockIdx.y * 64;
    const int tid = threadIdx.x;
    const int tm = (tid >> 4) << 2;
    const int tn = (tid & 15) << 2;
    float acc[4][4] = {{0.f,0.f,0.f,0.f},{0.f,0.f,0.f,0.f},
                       {0.f,0.f,0.f,0.f},{0.f,0.f,0.f,0.f}};

    for (int k0 = 0; k0 < K; k0 += 16) {
#pragma unroll
        for (int i = 0; i < 4; ++i) {
            int idx = tid + i * 256;
            int row = idx >> 4, col = idx & 15;
            int gm = bm + row, gk = k0 + col;
            As[col][row] = (gm < M && gk < K) ? A[(size_t)gm * K + gk] : 0.f;
        }
#pragma unroll
        for (int i = 0; i < 4; ++i) {
            int idx = tid + i * 256;
            int row = idx >> 4, col = idx & 15;
            int gn = bn + row, gk = k0 + col;
            Bs[col][row] = (gn < N && gk < K) ? B[(size_t)gn * ldb + gk] : 0.f;
        }
        __syncthreads();
#pragma unroll
        for (int kk = 0; kk < 16; ++kk) {
            const float4 a4 = *(const float4*)&As[kk][tm];
            const float4 b4 = *(const float4*)&Bs[kk][tn];
            const float av[4] = {a4.x, a4.y, a4.z, a4.w};
            const float bv[4] = {b4.x, b4.y, b4.z, b4.w};
#pragma unroll
            for (int i = 0; i < 4; ++i)
#pragma unroll
                for (int j = 0; j < 4; ++j)
                    acc[i][j] += av[i] * bv[j];
        }
        __syncthreads();
    }
#pragma unroll
    for (int i = 0; i < 4; ++i) {
        int gm = bm + tm + i;
        if (gm >= M) continue;
#pragma unroll
        for (int j = 0; j < 4; ++j) {
            int gn = bn + tn + j;
            if (gn >= N) continue;
            float v = acc[i][j];
            if (bias) v += bias[gn];
            if (do_relu) v = fmaxf(v, 0.f);
            C[(size_t)gm * N + gn] = v;
        }
    }
}

// ---------------------------------------------------------------------------
__global__ __launch_bounds__(64) void ffn2_k(
    const float* __restrict__ h1, const float* __restrict__ w2,
    const float* __restrict__ b2, float* __restrict__ out, int B)
{
    const int b = blockIdx.x;
    float s = 0.f;
    for (int k = threadIdx.x; k < HID; k += 64)
        s += h1[(size_t)b * HID + k] * w2[k];
#pragma unroll
    for (int off = 32; off > 0; off >>= 1) s += __shfl_down(s, off);
    if (threadIdx.x == 0) out[b] = s + b2[0];
}

// ---------------------------------------------------------------------------
extern "C" void kernel_launch(void* const* d_in, const int* in_sizes, int n_in,
                              void* d_out, int out_size, void* d_ws, size_t ws_size,
                              hipStream_t stream)
{
    float* outp = (float*)d_out;
    const int fillBlocks = (out_size + 255) / 256;

    if (n_in < 12) {
        fill_f32<<<fillBlocks, 256, 0, stream>>>(outp, out_size, 2.0e6f + n_in);
        return;
    }

    const int N = in_sizes[0] / 133;   // atoms
    const int E = in_sizes[1] / 2;     // edges
    const int B = out_size;            // molecules

    const long long expect[12] = {
        (long long)N * 133, (long long)E * 2, (long long)E * 14, N,
        300LL * 147, 300LL * 300, 300LL * 433, 300,
        300LL * 300, 300, 300, 1 };
    for (int i = 0; i < 12; ++i) {
        if ((long long)in_sizes[i] != expect[i]) {
            fill_f32<<<fillBlocks, 256, 0, stream>>>(outp, out_size,
                                                     3.0e6f + 1.0e4f * i);
            return;
        }
    }

    // ---- workspace layout --------------------------------------------------
    // [0,64e6)     xa   f16 [N,320]
    // [64,128e6)   nei  f16 [N,320]  (accumulator, reused all 3 passes)
    // [128,192e6)  hn1  f16 [N,320]  (later atom_h)
    // [192,256e6)  hn0  f16 [N,320]
    // [256e6...)   WiA[320][144], Wh[320][320], WoA[320][144], WoB[320][320],
    //              mol f32 [B,300], h1 f32 [B,300]
    char* base = (char*)d_ws;
    const size_t atomF16  = (size_t)N * HIDP * sizeof(f16);   // 64e6
    const size_t molBytes = (size_t)B * HID * sizeof(float);
    const size_t wiB  = 320 * 144 * sizeof(f16);
    const size_t whB  = 320 * 320 * sizeof(f16);
    const size_t woAB = 320 * 144 * sizeof(f16);
    const size_t woBB = 320 * 320 * sizeof(f16);
    const size_t need = 4 * atomF16 + wiB + whB + woAB + woBB + 2 * molBytes;

    if (ws_size < need) {
        fill_f32<<<fillBlocks, 256, 0, stream>>>(outp, out_size,
                                                 (float)(ws_size >> 20));
        return;
    }

    const float* x     = (const float*)d_in[0];
    const int*   ei    = (const int*)d_in[1];
    const float* ea    = (const float*)d_in[2];
    const int*   batch = (const int*)d_in[3];
    const float* W_i   = (const float*)d_in[4];
    const float* W_h   = (const float*)d_in[5];
    const float* W_o   = (const float*)d_in[6];
    const float* W_ob  = (const float*)d_in[7];
    const float* f1w   = (const float*)d_in[8];
    const float* f1b   = (const float*)d_in[9];
    const float* f2w   = (const float*)d_in[10];
    const float* f2b   = (const float*)d_in[11];
    const int* src = ei;
    const int* tgt = ei + E;

    f16* xa   = (f16*)(base);
    f16* nei  = (f16*)(base + atomF16);
    f16* hn1  = (f16*)(base + 2 * atomF16);
    f16* hn0  = (f16*)(base + 3 * atomF16);
    f16* WiA  = (f16*)(base + 4 * atomF16);
    f16* Wh   = (f16*)((char*)WiA + wiB);
    f16* WoA  = (f16*)((char*)Wh + whB);
    f16* WoB  = (f16*)((char*)WoA + woAB);
    float* mol = (float*)((char*)WoB + woBB);
    float* h1  = mol + (size_t)B * HID;
    f16* atom_h = hn1;   // overlays hn1 after its last use

    const unsigned* xa_u  = (const unsigned*)xa;
    const unsigned* hn0_u = (const unsigned*)hn0;
    const unsigned* hn1_u = (const unsigned*)hn1;
    unsigned*       nei_u = (unsigned*)nei;

    const int gAtom = (N + 127) / 128;      // 782 blocks, 512 threads
    const dim3 gMol((B + 63) / 64, (HID + 63) / 64);
    const int EDGE_BLOCKS = 16384;
    const int ZERO_BLOCKS = 2048;
    const size_t nei4 = atomF16 / 16;

    // 0. weights -> padded f16 [320][kpad]
    cvt_pad_f16<<<64,  256, 0, stream>>>(WiA, W_i,       300, 147, 133, 144, 320);
    cvt_pad_f16<<<128, 256, 0, stream>>>(Wh,  W_h,       300, 300, 300, 320, 320);
    cvt_pad_f16<<<64,  256, 0, stream>>>(WoA, W_o,       300, 433, 133, 144, 320);
    cvt_pad_f16<<<128, 256, 0, stream>>>(WoB, W_o + 133, 300, 433, 300, 320, 320);

    // 1. xa = x @ W_i[:, :133]^T   (f16 out, no relu)
    gemm_mfma<<<gAtom, 512, 0, stream>>>(x, 133, 0, 133, WiA, 144,
        nullptr, 0, 0, 0, nullptr, 0, nullptr, xa, N, 0);
    // 2. nei0 = segsum(m0)
    zero16<<<ZERO_BLOCKS, 256, 0, stream>>>((float4*)nei, nei4);
    edge_pass<<<EDGE_BLOCKS, 192, 0, stream>>>(xa_u, nullptr, nullptr, src, tgt,
        ea, W_i, nei_u, E, N);
    // 3. hn0 = nei0 @ W_h^T
    gemm_mfma<<<gAtom, 512, 0, stream>>>(nei, HIDP, 1, HIDP, Wh, 320,
        nullptr, 0, 0, 0, nullptr, 0, nullptr, hn0, N, 0);
    // 4. nei1 = segsum(m1)
    zero16<<<ZERO_BLOCKS, 256, 0, stream>>>((float4*)nei, nei4);
    edge_pass<<<EDGE_BLOCKS, 192, 0, stream>>>(xa_u, hn0_u, nullptr, src, tgt,
        ea, W_i, nei_u, E, N);
    // 5. hn1 = nei1 @ W_h^T
    gemm_mfma<<<gAtom, 512, 0, stream>>>(nei, HIDP, 1, HIDP, Wh, 320,
        nullptr, 0, 0, 0, nullptr, 0, nullptr, hn1, N, 0);
    // 6. atom_msg = segsum(m2)
    zero16<<<ZERO_BLOCKS, 256, 0, stream>>>((float4*)nei, nei4);
    edge_pass<<<EDGE_BLOCKS, 192, 0, stream>>>(xa_u, hn0_u, hn1_u, src, tgt,
        ea, W_i, nei_u, E, N);
    // 7. atom_h = relu(x @ WoA^T + msg @ WoB^T + b)  (two-phase, f16 -> hn1 buf)
    gemm_mfma<<<gAtom, 512, 0, stream>>>(x, 133, 0, 133, WoA, 144,
        nei, HIDP, 1, HIDP, WoB, 320, W_ob, atom_h, N, 1);
    // 8. mol[b] = segment_sum(atom_h)
    mol_pool<<<B, 256, 0, stream>>>(atom_h, batch, mol, N);
    // 9. h1 = relu(mol @ ffn1^T + b1)
    gemm_f32s<<<gMol, 256, 0, stream>>>(mol, HID, f1w, HID, f1b, h1, B, HID, 1);
    // 10. out = h1 @ ffn2^T + b2
    ffn2_k<<<B, 64, 0, stream>>>(h1, f2w, f2b, outp, B);
}

// Round 7
// 1303.161 us; speedup vs baseline: 2.9746x; 1.0116x over previous
//
#include <hip/hip_runtime.h>
#include <hip/hip_fp16.h>

#define HID   300
#define HIDP  320            // padded hidden (nei rows)
#define PSTR  900            // packed row stride in f16 (3 slots x 300)
#define APB   8              // atoms per block in edge_csr

typedef _Float16 f16;
typedef f16  f16x4 __attribute__((ext_vector_type(4)));
typedef float f32x4 __attribute__((ext_vector_type(4)));

// ---------------------------------------------------------------------------
// helpers
// ---------------------------------------------------------------------------
__device__ __forceinline__ float f16lo(unsigned u) {
    union { unsigned short s; f16 h; } c; c.s = (unsigned short)(u & 0xffffu);
    return (float)c.h;
}
__device__ __forceinline__ float f16hi(unsigned u) {
    union { unsigned short s; f16 h; } c; c.s = (unsigned short)(u >> 16);
    return (float)c.h;
}
__device__ __forceinline__ unsigned pk16(float a, float b) {
    union { f16 h[2]; unsigned u; } c; c.h[0] = (f16)a; c.h[1] = (f16)b;
    return c.u;
}

// ---------------------------------------------------------------------------
__global__ __launch_bounds__(256) void fill_f32(float* __restrict__ p, int n, float v)
{
    int i = blockIdx.x * blockDim.x + threadIdx.x;
    int stride = gridDim.x * blockDim.x;
    for (; i < n; i += stride) p[i] = v;
}

__global__ __launch_bounds__(256) void zero_i32(int* __restrict__ p, int n)
{
    int i = blockIdx.x * blockDim.x + threadIdx.x;
    int stride = gridDim.x * blockDim.x;
    for (; i < n; i += stride) p[i] = 0;
}

// dst [dstRows][kpad] f16 zero-padded; src fp32 [srcRows][ldsrc], kuse cols used
__global__ __launch_bounds__(256) void cvt_pad_f16(
    f16* __restrict__ dst, const float* __restrict__ src,
    int srcRows, int ldsrc, int kuse, int kpad, int dstRows)
{
    int i = blockIdx.x * 256 + threadIdx.x;
    const int total = dstRows * kpad;
    const int st = gridDim.x * 256;
    for (; i < total; i += st) {
        int r = i / kpad, k = i - r * kpad;
        dst[i] = (r < srcRows && k < kuse) ? (f16)src[(size_t)r * ldsrc + k]
                                           : (f16)0.f;
    }
}

// ---------------------------------------------------------------------------
// CSR build: histogram -> single-block scan -> scatter
// ---------------------------------------------------------------------------
__global__ __launch_bounds__(256) void hist_tgt(
    const int* __restrict__ tgt, int* __restrict__ deg, int E, int N)
{
    int e = blockIdx.x * 256 + threadIdx.x;
    const int st = gridDim.x * 256;
    for (; e < E; e += st) {
        int t = tgt[e];
        t = ((unsigned)t < (unsigned)N) ? t : 0;
        atomicAdd(&deg[t], 1);
    }
}

__global__ __launch_bounds__(1024) void scan_deg(
    const int* __restrict__ deg, int* __restrict__ rowPtr,
    int* __restrict__ cursor, int N, int E)
{
    __shared__ int sums[1024];
    const int t = threadIdx.x;
    const int C = (N + 1023) >> 10;
    const int b0 = t * C;
    const int b1 = min(b0 + C, N);
    int s = 0;
    for (int i = b0; i < b1; ++i) s += deg[i];
    sums[t] = s;
    __syncthreads();
    for (int off = 1; off < 1024; off <<= 1) {
        int v = (t >= off) ? sums[t - off] : 0;
        __syncthreads();
        sums[t] += v;
        __syncthreads();
    }
    int run = (t == 0) ? 0 : sums[t - 1];
    for (int i = b0; i < b1; ++i) {
        rowPtr[i] = run;
        cursor[i] = run;
        run += deg[i];
    }
    if (t == 0) rowPtr[N] = E;
}

__global__ __launch_bounds__(256) void scatter_e(
    const int* __restrict__ src, const int* __restrict__ tgt,
    int* __restrict__ cursor, int* __restrict__ csrc, int* __restrict__ ceid,
    int E, int N)
{
    int e = blockIdx.x * 256 + threadIdx.x;
    const int st = gridDim.x * 256;
    for (; e < E; e += st) {
        int t = tgt[e];
        int s = src[e];
        t = ((unsigned)t < (unsigned)N) ? t : 0;
        s = ((unsigned)s < (unsigned)N) ? s : 0;
        const int p = atomicAdd(&cursor[t], 1);
        csrc[p] = s;
        ceid[p] = e;
    }
}

// ---------------------------------------------------------------------------
// MFMA GEMM (two-phase): C = act( A1@W1^T + A2@W2^T + bias ), 300 out cols.
// A fp32 (guarded, Kuse cols) or f16 (unguarded, padded rows, stride lda).
// W f16 [320][kpad] zero-padded. C: f16, row stride ldc, cols n<300 written.
// Block: 512 thr = 8 waves, BM=128, BK=16, double-buffered LDS.
// ---------------------------------------------------------------------------
__global__ __launch_bounds__(512) void gemm_mfma(
    const void* __restrict__ A1, int lda1, int a1f16, int K1use,
    const f16* __restrict__ W1, int kpad1,
    const void* __restrict__ A2, int lda2, int a2f16, int K2use,
    const f16* __restrict__ W2, int kpad2,
    const float* __restrict__ bias,
    f16* __restrict__ C, int ldc,
    int M, int do_relu)
{
    __shared__ f16 As[2][128][20];
    __shared__ f16 Ws[2][320][20];

    const int tid  = threadIdx.x;
    const int bm   = blockIdx.x * 128;
    const int lane = tid & 63;
    const int wv   = tid >> 6;          // 0..7
    const int wrow = (wv >> 2) * 64;    // 0 / 64
    const int wcol = (wv & 3) * 80;     // 0/80/160/240
    const int lm   = lane & 15;
    const int lk   = (lane >> 4) << 2;

    const int n1 = A1 ? (kpad1 >> 4) : 0;
    const int n2 = A2 ? (kpad2 >> 4) : 0;
    const int ntot = n1 + n2;

    f32x4 acc[4][5];
#pragma unroll
    for (int r = 0; r < 4; ++r)
#pragma unroll
        for (int c = 0; c < 5; ++c) acc[r][c] = (f32x4){0.f, 0.f, 0.f, 0.f};

    const int arow = tid >> 2;          // 0..127
    const int akg  = (tid & 3) << 2;    // 0/4/8/12

    auto stage = [&](int s, int b) {
        const void* A; int lda, af16, Kuse, kpad; const f16* W; int k0;
        if (s < n1) { A = A1; lda = lda1; af16 = a1f16; Kuse = K1use;
                      W = W1; kpad = kpad1; k0 = s << 4; }
        else        { A = A2; lda = lda2; af16 = a2f16; Kuse = K2use;
                      W = W2; kpad = kpad2; k0 = (s - n1) << 4; }
        const int gm = bm + arow;
        const int gk = k0 + akg;
        f16x4 va = (f16x4){0, 0, 0, 0};
        if (gm < M) {
            if (af16) {
                va = *(const f16x4*)((const f16*)A + (size_t)gm * lda + gk);
            } else {
                const float* p = (const float*)A + (size_t)gm * lda + gk;
#pragma unroll
                for (int j = 0; j < 4; ++j)
                    va[j] = (gk + j < Kuse) ? (f16)p[j] : (f16)0.f;
            }
        }
        *(f16x4*)&As[b][arow][akg] = va;
#pragma unroll
        for (int it = 0; it < 3; ++it) {
            const int idx = tid + (it << 9);
            if (idx < 1280) {
                const int wr = idx >> 2, kg = (idx & 3) << 2;
                *(f16x4*)&Ws[b][wr][kg] =
                    *(const f16x4*)(W + (size_t)wr * kpad + k0 + kg);
            }
        }
    };

    auto compute = [&](int b) {
        f16x4 af[4], bf[5];
#pragma unroll
        for (int r = 0; r < 4; ++r)
            af[r] = *(const f16x4*)&As[b][wrow + (r << 4) + lm][lk];
#pragma unroll
        for (int c = 0; c < 5; ++c)
            bf[c] = *(const f16x4*)&Ws[b][wcol + (c << 4) + lm][lk];
#pragma unroll
        for (int r = 0; r < 4; ++r)
#pragma unroll
            for (int c = 0; c < 5; ++c)
                acc[r][c] = __builtin_amdgcn_mfma_f32_16x16x16f16(
                    af[r], bf[c], acc[r][c], 0, 0, 0);
    };

    int b = 0;
    stage(0, 0);
    for (int s = 0; s < ntot; ++s) {
        __syncthreads();
        if (s + 1 < ntot) stage(s + 1, b ^ 1);
        compute(b);
        b ^= 1;
    }

    // epilogue: C/D frag col = lane&15, row = 4*(lane>>4)+i ; only n<300 stored
#pragma unroll
    for (int r = 0; r < 4; ++r) {
        const int gm0 = bm + wrow + (r << 4) + ((lane >> 4) << 2);
#pragma unroll
        for (int c = 0; c < 5; ++c) {
            const int n = wcol + (c << 4) + lm;
            if (n >= HID) continue;
            const float bi = bias ? bias[n] : 0.f;
#pragma unroll
            for (int i = 0; i < 4; ++i) {
                const int gm = gm0 + i;
                if (gm >= M) continue;
                float v = acc[r][c][i] + bi;
                if (do_relu) v = fmaxf(v, 0.f);
                C[(size_t)gm * ldc + n] = (f16)v;
            }
        }
    }
}

// ---------------------------------------------------------------------------
// edge_csr: per target atom, accumulate messages from incoming edges in fp32
// registers, store one coalesced row. No atomics.
//   m = relu(packed[s,slot0] + ea[e] @ Wi_bond^T)
//       [relu(+packed[s,slot1])]  [relu(+packed[s,slot2])]
// Block handles APB atoms; thread p = channel pair (2p, 2p+1).
// ---------------------------------------------------------------------------
__global__ __launch_bounds__(192) void edge_csr(
    const unsigned* __restrict__ packed,  // [N][450] u32 pairs (slots +0/+150/+300)
    const int* __restrict__ rowPtr,
    const int* __restrict__ csrc,
    const int* __restrict__ ceid,
    const float* __restrict__ ea,         // [E,14]
    const float* __restrict__ Wi,         // [300,147] fp32 (bond cols 133..146)
    unsigned* __restrict__ out,           // nei [N][160] u32 pairs (320 f16)
    int nslots, int N)
{
    const int p = threadIdx.x;
    float w0[14], w1[14];
    if (p < 150) {
#pragma unroll
        for (int k = 0; k < 14; ++k) {
            w0[k] = Wi[(2 * p) * 147 + 133 + k];
            w1[k] = Wi[(2 * p + 1) * 147 + 133 + k];
        }
    }
    const int a0 = blockIdx.x * APB;
    const int a1 = min(a0 + APB, N);
    for (int a = a0; a < a1; ++a) {
        const int beg = rowPtr[a];
        const int end = rowPtr[a + 1];
        float acc0 = 0.f, acc1 = 0.f;
        if (p < 150) {
            for (int j = beg; j < end; ++j) {
                const int s = csrc[j];
                const int e = ceid[j];
                const unsigned* row = packed + (size_t)s * (PSTR / 2);
                unsigned u = row[p];
                float v0 = f16lo(u), v1 = f16hi(u);
#pragma unroll
                for (int k = 0; k < 14; ++k) {
                    const float ev = ea[(size_t)e * 14 + k];
                    v0 += ev * w0[k];
                    v1 += ev * w1[k];
                }
                v0 = fmaxf(v0, 0.f); v1 = fmaxf(v1, 0.f);
                if (nslots > 1) {
                    u = row[p + 150];
                    v0 = fmaxf(v0 + f16lo(u), 0.f);
                    v1 = fmaxf(v1 + f16hi(u), 0.f);
                }
                if (nslots > 2) {
                    u = row[p + 300];
                    v0 = fmaxf(v0 + f16lo(u), 0.f);
                    v1 = fmaxf(v1 + f16hi(u), 0.f);
                }
                acc0 += v0; acc1 += v1;
            }
        }
        if (p < HIDP / 2)
            out[(size_t)a * (HIDP / 2) + p] = (p < 150) ? pk16(acc0, acc1) : 0u;
    }
}

// ---------------------------------------------------------------------------
// mol_pool: mol[b,:300] = sum of atom_h rows (f16, stride PSTR) with batch==b
// ---------------------------------------------------------------------------
__global__ __launch_bounds__(256) void mol_pool(
    const f16* __restrict__ ah,       // packed slot1: [N] rows stride 900
    const int* __restrict__ batch,    // [N], sorted
    float* __restrict__ mol,          // [B,300]
    int N)
{
    const int b = blockIdx.x;
    int lo = 0, hi = N;
    while (lo < hi) { int mid = (lo + hi) >> 1; if (batch[mid] < b) lo = mid + 1; else hi = mid; }
    const int start = lo;
    hi = N;
    while (lo < hi) { int mid = (lo + hi) >> 1; if (batch[mid] < b + 1) lo = mid + 1; else hi = mid; }
    const int end = lo;

    for (int h = threadIdx.x; h < HID; h += 256) {
        float s = 0.f;
        for (int a = start; a < end; ++a) s += (float)ah[(size_t)a * PSTR + h];
        mol[(size_t)b * HID + h] = s;
    }
}

// ---------------------------------------------------------------------------
// small fp32 GEMM (mol FFN1): C = relu(A @ B^T + bias)
// ---------------------------------------------------------------------------
__global__ __launch_bounds__(256) void gemm_f32s(
    const float* __restrict__ A, int K,
    const float* __restrict__ B, int ldb,
    const float* __restrict__ bias,
    float* __restrict__ C, int M, int N, int do_relu)
{
    __shared__ float As[16][68];
    __shared__ float Bs[16][68];
    const int bm = blockIdx.x * 64;
    const int bn = blockIdx.y * 64;
    const int tid = threadIdx.x;
    const int tm = (tid >> 4) << 2;
    const int tn = (tid & 15) << 2;
    float acc[4][4] = {{0.f,0.f,0.f,0.f},{0.f,0.f,0.f,0.f},
                       {0.f,0.f,0.f,0.f},{0.f,0.f,0.f,0.f}};

    for (int k0 = 0; k0 < K; k0 += 16) {
#pragma unroll
        for (int i = 0; i < 4; ++i) {
            int idx = tid + i * 256;
            int row = idx >> 4, col = idx & 15;
            int gm = bm + row, gk = k0 + col;
            As[col][row] = (gm < M && gk < K) ? A[(size_t)gm * K + gk] : 0.f;
        }
#pragma unroll
        for (int i = 0; i < 4; ++i) {
            int idx = tid + i * 256;
            int row = idx >> 4, col = idx & 15;
            int gn = bn + row, gk = k0 + col;
            Bs[col][row] = (gn < N && gk < K) ? B[(size_t)gn * ldb + gk] : 0.f;
        }
        __syncthreads();
#pragma unroll
        for (int kk = 0; kk < 16; ++kk) {
            const float4 a4 = *(const float4*)&As[kk][tm];
            const float4 b4 = *(const float4*)&Bs[kk][tn];
            const float av[4] = {a4.x, a4.y, a4.z, a4.w};
            const float bv[4] = {b4.x, b4.y, b4.z, b4.w};
#pragma unroll
            for (int i = 0; i < 4; ++i)
#pragma unroll
                for (int j = 0; j < 4; ++j)
                    acc[i][j] += av[i] * bv[j];
        }
        __syncthreads();
    }
#pragma unroll
    for (int i = 0; i < 4; ++i) {
        int gm = bm + tm + i;
        if (gm >= M) continue;
#pragma unroll
        for (int j = 0; j < 4; ++j) {
            int gn = bn + tn + j;
            if (gn >= N) continue;
            float v = acc[i][j];
            if (bias) v += bias[gn];
            if (do_relu) v = fmaxf(v, 0.f);
            C[(size_t)gm * N + gn] = v;
        }
    }
}

// ---------------------------------------------------------------------------
__global__ __launch_bounds__(64) void ffn2_k(
    const float* __restrict__ h1, const float* __restrict__ w2,
    const float* __restrict__ b2, float* __restrict__ out, int B)
{
    const int b = blockIdx.x;
    float s = 0.f;
    for (int k = threadIdx.x; k < HID; k += 64)
        s += h1[(size_t)b * HID + k] * w2[k];
#pragma unroll
    for (int off = 32; off > 0; off >>= 1) s += __shfl_down(s, off);
    if (threadIdx.x == 0) out[b] = s + b2[0];
}

// ---------------------------------------------------------------------------
extern "C" void kernel_launch(void* const* d_in, const int* in_sizes, int n_in,
                              void* d_out, int out_size, void* d_ws, size_t ws_size,
                              hipStream_t stream)
{
    float* outp = (float*)d_out;
    const int fillBlocks = (out_size + 255) / 256;

    if (n_in < 12) {
        fill_f32<<<fillBlocks, 256, 0, stream>>>(outp, out_size, 2.0e6f + n_in);
        return;
    }

    const int N = in_sizes[0] / 133;   // atoms
    const int E = in_sizes[1] / 2;     // edges
    const int B = out_size;            // molecules

    const long long expect[12] = {
        (long long)N * 133, (long long)E * 2, (long long)E * 14, N,
        300LL * 147, 300LL * 300, 300LL * 433, 300,
        300LL * 300, 300, 300, 1 };
    for (int i = 0; i < 12; ++i) {
        if ((long long)in_sizes[i] != expect[i]) {
            fill_f32<<<fillBlocks, 256, 0, stream>>>(outp, out_size,
                                                     3.0e6f + 1.0e4f * i);
            return;
        }
    }

    // ---- workspace layout ---------------------------------------------------
    // packed f16 [N][900]  (slot0=xa, slot1=hn0/atom_h, slot2=hn1)   180.0 MB
    // nei    f16 [N][320]                                             64.0 MB
    // weights WiA[320][144], Wh[320][320], WoA[320][144], WoB[320][320] 0.59 MB
    // mol f32 [B,300], h1 f32 [B,300]                                  9.83 MB
    // rowPtr[N+1], cursor[N], deg[N], csrc[E], ceid[E]                 4.4 MB
    char* basep = (char*)d_ws;
    auto align16 = [](size_t v) { return (v + 15) & ~(size_t)15; };
    const size_t packedB = align16((size_t)N * PSTR * sizeof(f16));
    const size_t neiB    = align16((size_t)N * HIDP * sizeof(f16));
    const size_t wiB  = align16(320 * 144 * sizeof(f16));
    const size_t whB  = align16(320 * 320 * sizeof(f16));
    const size_t molB = align16((size_t)B * HID * sizeof(float));
    const size_t rpB  = align16((size_t)(N + 1) * sizeof(int));
    const size_t curB = align16((size_t)N * sizeof(int));
    const size_t ceB  = align16((size_t)E * sizeof(int));
    const size_t need = packedB + neiB + wiB + whB + wiB + whB
                      + 2 * molB + rpB + 2 * curB + 2 * ceB;

    if (ws_size < need) {
        fill_f32<<<fillBlocks, 256, 0, stream>>>(outp, out_size,
                                                 (float)(ws_size >> 20));
        return;
    }

    const float* x     = (const float*)d_in[0];
    const int*   ei    = (const int*)d_in[1];
    const float* ea    = (const float*)d_in[2];
    const int*   batch = (const int*)d_in[3];
    const float* W_i   = (const float*)d_in[4];
    const float* W_h   = (const float*)d_in[5];
    const float* W_o   = (const float*)d_in[6];
    const float* W_ob  = (const float*)d_in[7];
    const float* f1w   = (const float*)d_in[8];
    const float* f1b   = (const float*)d_in[9];
    const float* f2w   = (const float*)d_in[10];
    const float* f2b   = (const float*)d_in[11];
    const int* src = ei;
    const int* tgt = ei + E;

    char* cur_p = basep;
    f16* packed = (f16*)cur_p;          cur_p += packedB;
    f16* nei    = (f16*)cur_p;          cur_p += neiB;
    f16* WiA    = (f16*)cur_p;          cur_p += wiB;
    f16* Wh     = (f16*)cur_p;          cur_p += whB;
    f16* WoA    = (f16*)cur_p;          cur_p += wiB;
    f16* WoB    = (f16*)cur_p;          cur_p += whB;
    float* mol  = (float*)cur_p;        cur_p += molB;
    float* h1   = (float*)cur_p;        cur_p += molB;
    int* rowPtr = (int*)cur_p;          cur_p += rpB;
    int* cursor = (int*)cur_p;          cur_p += curB;
    int* deg    = (int*)cur_p;          cur_p += curB;
    int* csrc   = (int*)cur_p;          cur_p += ceB;
    int* ceid   = (int*)cur_p;          cur_p += ceB;

    f16* xa_s  = packed;          // slot 0
    f16* hn0_s = packed + 300;    // slot 1 (later atom_h)
    f16* hn1_s = packed + 600;    // slot 2

    const unsigned* packed_u = (const unsigned*)packed;
    unsigned*       nei_u    = (unsigned*)nei;

    const int gAtom = (N + 127) / 128;
    const int gEdge = (N + APB - 1) / APB;
    const dim3 gMol((B + 63) / 64, (HID + 63) / 64);

    // --- CSR build ---
    zero_i32<<<128, 256, 0, stream>>>(deg, N);
    hist_tgt<<<1024, 256, 0, stream>>>(tgt, deg, E, N);
    scan_deg<<<1, 1024, 0, stream>>>(deg, rowPtr, cursor, N, E);
    scatter_e<<<1024, 256, 0, stream>>>(src, tgt, cursor, csrc, ceid, E, N);

    // --- weights -> padded f16 ---
    cvt_pad_f16<<<64,  256, 0, stream>>>(WiA, W_i,       300, 147, 133, 144, 320);
    cvt_pad_f16<<<128, 256, 0, stream>>>(Wh,  W_h,       300, 300, 300, 320, 320);
    cvt_pad_f16<<<64,  256, 0, stream>>>(WoA, W_o,       300, 433, 133, 144, 320);
    cvt_pad_f16<<<128, 256, 0, stream>>>(WoB, W_o + 133, 300, 433, 300, 320, 320);

    // 1. xa = x @ W_i[:, :133]^T -> packed slot0
    gemm_mfma<<<gAtom, 512, 0, stream>>>(x, 133, 0, 133, WiA, 144,
        nullptr, 0, 0, 0, nullptr, 0, nullptr, xa_s, PSTR, N, 0);
    // 2. nei0 = segsum(m0)
    edge_csr<<<gEdge, 192, 0, stream>>>(packed_u, rowPtr, csrc, ceid, ea, W_i,
                                        nei_u, 1, N);
    // 3. hn0 = nei0 @ W_h^T -> packed slot1
    gemm_mfma<<<gAtom, 512, 0, stream>>>(nei, HIDP, 1, HIDP, Wh, 320,
        nullptr, 0, 0, 0, nullptr, 0, nullptr, hn0_s, PSTR, N, 0);
    // 4. nei1 = segsum(m1)
    edge_csr<<<gEdge, 192, 0, stream>>>(packed_u, rowPtr, csrc, ceid, ea, W_i,
                                        nei_u, 2, N);
    // 5. hn1 = nei1 @ W_h^T -> packed slot2
    gemm_mfma<<<gAtom, 512, 0, stream>>>(nei, HIDP, 1, HIDP, Wh, 320,
        nullptr, 0, 0, 0, nullptr, 0, nullptr, hn1_s, PSTR, N, 0);
    // 6. atom_msg = segsum(m2)
    edge_csr<<<gEdge, 192, 0, stream>>>(packed_u, rowPtr, csrc, ceid, ea, W_i,
                                        nei_u, 3, N);
    // 7. atom_h = relu(x @ WoA^T + msg @ WoB^T + b) -> packed slot1
    gemm_mfma<<<gAtom, 512, 0, stream>>>(x, 133, 0, 133, WoA, 144,
        nei, HIDP, 1, HIDP, WoB, 320, W_ob, hn0_s, PSTR, N, 1);
    // 8. mol[b] = segment_sum(atom_h)
    mol_pool<<<B, 256, 0, stream>>>(hn0_s, batch, mol, N);
    // 9. h1 = relu(mol @ ffn1^T + b1)
    gemm_f32s<<<gMol, 256, 0, stream>>>(mol, HID, f1w, HID, f1b, h1, B, HID, 1);
    // 10. out = h1 @ ffn2^T + b2
    ffn2_k<<<B, 64, 0, stream>>>(h1, f2w, f2b, outp, B);
}

// Round 8
// 1113.186 us; speedup vs baseline: 3.4822x; 1.1707x over previous
//
#include <hip/hip_runtime.h>
#include <hip/hip_fp16.h>

#define HID   300
#define NEIP  304            // nei row stride (f16), mult of 16
#define PSTR  900            // packed row stride in f16 (3 slots x 300)
#define APB   4              // atoms per block in edge_csr

typedef _Float16 f16;
typedef f16  f16x2 __attribute__((ext_vector_type(2)));
typedef f16  f16x4 __attribute__((ext_vector_type(4)));
typedef float f32x4 __attribute__((ext_vector_type(4)));

// ---------------------------------------------------------------------------
// helpers
// ---------------------------------------------------------------------------
__device__ __forceinline__ f16x2 u2h(unsigned u) {
    union { unsigned u; f16x2 h; } c; c.u = u; return c.h;
}
__device__ __forceinline__ unsigned pk16(float a, float b) {
    union { f16 h[2]; unsigned u; } c; c.h[0] = (f16)a; c.h[1] = (f16)b;
    return c.u;
}

// ---------------------------------------------------------------------------
__global__ __launch_bounds__(256) void fill_f32(float* __restrict__ p, int n, float v)
{
    int i = blockIdx.x * blockDim.x + threadIdx.x;
    int stride = gridDim.x * blockDim.x;
    for (; i < n; i += stride) p[i] = v;
}

__global__ __launch_bounds__(256) void zero_i32(int* __restrict__ p, int n)
{
    int i = blockIdx.x * blockDim.x + threadIdx.x;
    int stride = gridDim.x * blockDim.x;
    for (; i < n; i += stride) p[i] = 0;
}

// dst [dstRows][kpad] f16 zero-padded; src fp32 [srcRows][ldsrc], kuse cols used
__global__ __launch_bounds__(256) void cvt_pad_f16(
    f16* __restrict__ dst, const float* __restrict__ src,
    int srcRows, int ldsrc, int kuse, int kpad, int dstRows)
{
    int i = blockIdx.x * 256 + threadIdx.x;
    const int total = dstRows * kpad;
    const int st = gridDim.x * 256;
    for (; i < total; i += st) {
        int r = i / kpad, k = i - r * kpad;
        dst[i] = (r < srcRows && k < kuse) ? (f16)src[(size_t)r * ldsrc + k]
                                           : (f16)0.f;
    }
}

// ---------------------------------------------------------------------------
// CSR build: histogram -> single-block scan -> scatter (+ ea permute to f16)
// ---------------------------------------------------------------------------
__global__ __launch_bounds__(256) void hist_tgt(
    const int* __restrict__ tgt, int* __restrict__ deg, int E, int N)
{
    int e = blockIdx.x * 256 + threadIdx.x;
    const int st = gridDim.x * 256;
    for (; e < E; e += st) {
        int t = tgt[e];
        t = ((unsigned)t < (unsigned)N) ? t : 0;
        atomicAdd(&deg[t], 1);
    }
}

__global__ __launch_bounds__(1024) void scan_deg(
    const int* __restrict__ deg, int* __restrict__ rowPtr,
    int* __restrict__ cursor, int N, int E)
{
    __shared__ int sums[1024];
    const int t = threadIdx.x;
    const int C = (N + 1023) >> 10;
    const int b0 = t * C;
    const int b1 = min(b0 + C, N);
    int s = 0;
    for (int i = b0; i < b1; ++i) s += deg[i];
    sums[t] = s;
    __syncthreads();
    for (int off = 1; off < 1024; off <<= 1) {
        int v = (t >= off) ? sums[t - off] : 0;
        __syncthreads();
        sums[t] += v;
        __syncthreads();
    }
    int run = (t == 0) ? 0 : sums[t - 1];
    for (int i = b0; i < b1; ++i) {
        rowPtr[i] = run;
        cursor[i] = run;
        run += deg[i];
    }
    if (t == 0) rowPtr[N] = E;
}

__global__ __launch_bounds__(256) void scatter_e(
    const int* __restrict__ src, const int* __restrict__ tgt,
    const float* __restrict__ ea,
    int* __restrict__ cursor, int* __restrict__ csrc,
    unsigned* __restrict__ eaPk,    // [E][8] u32 (14 f16 + pad)
    int E, int N)
{
    int e = blockIdx.x * 256 + threadIdx.x;
    const int st = gridDim.x * 256;
    for (; e < E; e += st) {
        int t = tgt[e];
        int s = src[e];
        t = ((unsigned)t < (unsigned)N) ? t : 0;
        s = ((unsigned)s < (unsigned)N) ? s : 0;
        const int p = atomicAdd(&cursor[t], 1);
        csrc[p] = s;
        const float* er = ea + (size_t)e * 14;
        uint4 q0, q1;
        q0.x = pk16(er[0],  er[1]);  q0.y = pk16(er[2],  er[3]);
        q0.z = pk16(er[4],  er[5]);  q0.w = pk16(er[6],  er[7]);
        q1.x = pk16(er[8],  er[9]);  q1.y = pk16(er[10], er[11]);
        q1.z = pk16(er[12], er[13]); q1.w = 0u;
        uint4* dst = (uint4*)(eaPk + (size_t)p * 8);
        dst[0] = q0;
        dst[1] = q1;
    }
}

// ---------------------------------------------------------------------------
// MFMA GEMM (two-phase): C = act( A1@W1^T + A2@W2^T + bias ), 300 out cols.
// A fp32 (guarded, Kuse cols) or f16 (unguarded, padded rows, stride lda).
// W f16 [320][kpad] zero-padded. C: f16, row stride ldc, cols n<300 written.
// Block: 512 thr = 8 waves, BM=128, BK=16, double-buffered LDS.
// Fragments are ds_read BEFORE next-tile staging so MFMA never waits on the
// next tile's global loads (in-order lgkmcnt).
// ---------------------------------------------------------------------------
__global__ __launch_bounds__(512) void gemm_mfma(
    const void* __restrict__ A1, int lda1, int a1f16, int K1use,
    const f16* __restrict__ W1, int kpad1,
    const void* __restrict__ A2, int lda2, int a2f16, int K2use,
    const f16* __restrict__ W2, int kpad2,
    const float* __restrict__ bias,
    f16* __restrict__ C, int ldc,
    int M, int do_relu)
{
    __shared__ f16 As[2][128][20];
    __shared__ f16 Ws[2][320][20];

    const int tid  = threadIdx.x;
    const int bm   = blockIdx.x * 128;
    const int lane = tid & 63;
    const int wv   = tid >> 6;          // 0..7
    const int wrow = (wv >> 2) * 64;    // 0 / 64
    const int wcol = (wv & 3) * 80;     // 0/80/160/240
    const int lm   = lane & 15;
    const int lk   = (lane >> 4) << 2;

    const int n1 = A1 ? (kpad1 >> 4) : 0;
    const int n2 = A2 ? (kpad2 >> 4) : 0;
    const int ntot = n1 + n2;

    f32x4 acc[4][5];
#pragma unroll
    for (int r = 0; r < 4; ++r)
#pragma unroll
        for (int c = 0; c < 5; ++c) acc[r][c] = (f32x4){0.f, 0.f, 0.f, 0.f};

    const int arow = tid >> 2;          // 0..127
    const int akg  = (tid & 3) << 2;    // 0/4/8/12

    auto stage = [&](int s, int b) {
        const void* A; int lda, af16, Kuse, kpad; const f16* W; int k0;
        if (s < n1) { A = A1; lda = lda1; af16 = a1f16; Kuse = K1use;
                      W = W1; kpad = kpad1; k0 = s << 4; }
        else        { A = A2; lda = lda2; af16 = a2f16; Kuse = K2use;
                      W = W2; kpad = kpad2; k0 = (s - n1) << 4; }
        const int gm = bm + arow;
        const int gk = k0 + akg;
        f16x4 va = (f16x4){0, 0, 0, 0};
        if (gm < M) {
            if (af16) {
                va = *(const f16x4*)((const f16*)A + (size_t)gm * lda + gk);
            } else {
                const float* p = (const float*)A + (size_t)gm * lda + gk;
#pragma unroll
                for (int j = 0; j < 4; ++j)
                    va[j] = (gk + j < Kuse) ? (f16)p[j] : (f16)0.f;
            }
        }
        *(f16x4*)&As[b][arow][akg] = va;
#pragma unroll
        for (int it = 0; it < 3; ++it) {
            const int idx = tid + (it << 9);
            if (idx < 1280) {
                const int wr = idx >> 2, kg = (idx & 3) << 2;
                *(f16x4*)&Ws[b][wr][kg] =
                    *(const f16x4*)(W + (size_t)wr * kpad + k0 + kg);
            }
        }
    };

    int b = 0;
    stage(0, 0);
    for (int s = 0; s < ntot; ++s) {
        __syncthreads();
        // 1) fragments of current tile FIRST (ds_read)
        f16x4 af[4], bf[5];
#pragma unroll
        for (int r = 0; r < 4; ++r)
            af[r] = *(const f16x4*)&As[b][wrow + (r << 4) + lm][lk];
#pragma unroll
        for (int c = 0; c < 5; ++c)
            bf[c] = *(const f16x4*)&Ws[b][wcol + (c << 4) + lm][lk];
        // 2) issue next tile staging (global load + ds_write, other buffer)
        if (s + 1 < ntot) stage(s + 1, b ^ 1);
        // 3) MFMA on current fragments
#pragma unroll
        for (int r = 0; r < 4; ++r)
#pragma unroll
            for (int c = 0; c < 5; ++c)
                acc[r][c] = __builtin_amdgcn_mfma_f32_16x16x16f16(
                    af[r], bf[c], acc[r][c], 0, 0, 0);
        b ^= 1;
    }

    // epilogue: C/D frag col = lane&15, row = 4*(lane>>4)+i ; only n<300 stored
#pragma unroll
    for (int r = 0; r < 4; ++r) {
        const int gm0 = bm + wrow + (r << 4) + ((lane >> 4) << 2);
#pragma unroll
        for (int c = 0; c < 5; ++c) {
            const int n = wcol + (c << 4) + lm;
            if (n >= HID) continue;
            const float bi = bias ? bias[n] : 0.f;
#pragma unroll
            for (int i = 0; i < 4; ++i) {
                const int gm = gm0 + i;
                if (gm >= M) continue;
                float v = acc[r][c][i] + bi;
                if (do_relu) v = fmaxf(v, 0.f);
                C[(size_t)gm * ldc + n] = (f16)v;
            }
        }
    }
}

// ---------------------------------------------------------------------------
// edge_csr: per target atom, accumulate messages of incoming edges in fp32
// registers, store one coalesced row. Packed-f16 math, no atomics.
//   m = relu(packed[s,0] + eaPk[j] @ Wb^T); relu(+packed[s,1]); relu(+packed[s,2])
// Block handles APB atoms; thread p = channel pair (2p, 2p+1).
// ---------------------------------------------------------------------------
template <int NSLOTS>
__global__ __launch_bounds__(192) void edge_csr(
    const unsigned* __restrict__ packed,  // [N][450] u32 pairs (slots +0/+150/+300)
    const int* __restrict__ rowPtr,
    const int* __restrict__ csrc,
    const unsigned* __restrict__ eaPk,    // [E][8] u32 (14 f16)
    const float* __restrict__ Wi,         // [300,147] fp32 (bond cols 133..146)
    unsigned* __restrict__ out,           // nei [N][152] u32 pairs
    int N)
{
    const int p = threadIdx.x;
    f16x2 wpk[14];
    if (p < 150) {
#pragma unroll
        for (int k = 0; k < 14; ++k)
            wpk[k] = (f16x2){(f16)Wi[(2 * p) * 147 + 133 + k],
                             (f16)Wi[(2 * p + 1) * 147 + 133 + k]};
    }
    const f16x2 zero2 = (f16x2){(f16)0.f, (f16)0.f};

    const int a0 = blockIdx.x * APB;
    const int a1 = min(a0 + APB, N);
    for (int a = a0; a < a1; ++a) {
        const int beg = rowPtr[a];
        const int end = rowPtr[a + 1];
        float acc0 = 0.f, acc1 = 0.f;
        if (p < 150) {
#pragma unroll 2
            for (int j = beg; j < end; ++j) {
                const int s = csrc[j];
                const unsigned* row = packed + (size_t)s * (PSTR / 2);
                const unsigned u0 = row[p];
                unsigned u1 = 0, u2 = 0;
                if (NSLOTS > 1) u1 = row[p + 150];
                if (NSLOTS > 2) u2 = row[p + 300];
                const unsigned* eq = eaPk + (size_t)j * 8;
                f16x2 ebA = zero2, ebB = zero2;
#pragma unroll
                for (int k = 0; k < 7; ++k) {
                    const f16x2 e2 = u2h(eq[k]);
                    ebA += (f16x2){e2.x, e2.x} * wpk[2 * k];
                    ebB += (f16x2){e2.y, e2.y} * wpk[2 * k + 1];
                }
                f16x2 m = __builtin_elementwise_max(u2h(u0) + (ebA + ebB), zero2);
                if (NSLOTS > 1) m = __builtin_elementwise_max(m + u2h(u1), zero2);
                if (NSLOTS > 2) m = __builtin_elementwise_max(m + u2h(u2), zero2);
                acc0 += (float)m.x;
                acc1 += (float)m.y;
            }
        }
        if (p < NEIP / 2)
            out[(size_t)a * (NEIP / 2) + p] = (p < 150) ? pk16(acc0, acc1) : 0u;
    }
}

// ---------------------------------------------------------------------------
// mol_pool: mol[b,:300] = sum of atom_h rows (f16, stride PSTR) with batch==b
// ---------------------------------------------------------------------------
__global__ __launch_bounds__(256) void mol_pool(
    const f16* __restrict__ ah,       // packed slot1: [N] rows stride 900
    const int* __restrict__ batch,    // [N], sorted
    float* __restrict__ mol,          // [B,300]
    int N)
{
    const int b = blockIdx.x;
    int lo = 0, hi = N;
    while (lo < hi) { int mid = (lo + hi) >> 1; if (batch[mid] < b) lo = mid + 1; else hi = mid; }
    const int start = lo;
    hi = N;
    while (lo < hi) { int mid = (lo + hi) >> 1; if (batch[mid] < b + 1) lo = mid + 1; else hi = mid; }
    const int end = lo;

    for (int h = threadIdx.x; h < HID; h += 256) {
        float s = 0.f;
        for (int a = start; a < end; ++a) s += (float)ah[(size_t)a * PSTR + h];
        mol[(size_t)b * HID + h] = s;
    }
}

// ---------------------------------------------------------------------------
__global__ __launch_bounds__(64) void ffn2_k(
    const f16* __restrict__ h1,       // [B][304] f16
    const float* __restrict__ w2,     // [300]
    const float* __restrict__ b2, float* __restrict__ out, int B)
{
    const int b = blockIdx.x;
    float s = 0.f;
    for (int k = threadIdx.x; k < HID; k += 64)
        s += (float)h1[(size_t)b * NEIP + k] * w2[k];
#pragma unroll
    for (int off = 32; off > 0; off >>= 1) s += __shfl_down(s, off);
    if (threadIdx.x == 0) out[b] = s + b2[0];
}

// ---------------------------------------------------------------------------
extern "C" void kernel_launch(void* const* d_in, const int* in_sizes, int n_in,
                              void* d_out, int out_size, void* d_ws, size_t ws_size,
                              hipStream_t stream)
{
    float* outp = (float*)d_out;
    const int fillBlocks = (out_size + 255) / 256;

    if (n_in < 12) {
        fill_f32<<<fillBlocks, 256, 0, stream>>>(outp, out_size, 2.0e6f + n_in);
        return;
    }

    const int N = in_sizes[0] / 133;   // atoms
    const int E = in_sizes[1] / 2;     // edges
    const int B = out_size;            // molecules

    const long long expect[12] = {
        (long long)N * 133, (long long)E * 2, (long long)E * 14, N,
        300LL * 147, 300LL * 300, 300LL * 433, 300,
        300LL * 300, 300, 300, 1 };
    for (int i = 0; i < 12; ++i) {
        if ((long long)in_sizes[i] != expect[i]) {
            fill_f32<<<fillBlocks, 256, 0, stream>>>(outp, out_size,
                                                     3.0e6f + 1.0e4f * i);
            return;
        }
    }

    // ---- workspace layout ---------------------------------------------------
    // packed f16 [N][900] (slot0=xa, slot1=hn0/atom_h, slot2=hn1)    180.0 MB
    // nei    f16 [N][304]                                             60.8 MB
    // weights WiA[320][144] Wh[320][304] WoA[320][144] WoB[320][304]
    //         Wf1[320][304]                                            0.77 MB
    // mol f32 [B,300]  h1 f16 [B,304]                                  7.4 MB
    // rowPtr[N+1] cursor[N] deg[N] csrc[E] eaPk[E][8]u32              16.0 MB
    char* basep = (char*)d_ws;
    auto align16 = [](size_t v) { return (v + 15) & ~(size_t)15; };
    const size_t packedB = align16((size_t)N * PSTR * sizeof(f16));
    const size_t neiB    = align16((size_t)N * NEIP * sizeof(f16));
    const size_t wSmall  = align16(320 * 144 * sizeof(f16));
    const size_t wBig    = align16(320 * 304 * sizeof(f16));
    const size_t molB    = align16((size_t)B * HID * sizeof(float));
    const size_t h1B     = align16((size_t)B * NEIP * sizeof(f16));
    const size_t rpB     = align16((size_t)(N + 1) * sizeof(int));
    const size_t curB    = align16((size_t)N * sizeof(int));
    const size_t csrcB   = align16((size_t)E * sizeof(int));
    const size_t eaB     = align16((size_t)E * 8 * sizeof(unsigned));
    const size_t need = packedB + neiB + 2 * wSmall + 3 * wBig
                      + molB + h1B + rpB + 2 * curB + csrcB + eaB;

    if (ws_size < need) {
        fill_f32<<<fillBlocks, 256, 0, stream>>>(outp, out_size,
                                                 (float)(ws_size >> 20));
        return;
    }

    const float* x     = (const float*)d_in[0];
    const int*   ei    = (const int*)d_in[1];
    const float* ea    = (const float*)d_in[2];
    const int*   batch = (const int*)d_in[3];
    const float* W_i   = (const float*)d_in[4];
    const float* W_h   = (const float*)d_in[5];
    const float* W_o   = (const float*)d_in[6];
    const float* W_ob  = (const float*)d_in[7];
    const float* f1w   = (const float*)d_in[8];
    const float* f1b   = (const float*)d_in[9];
    const float* f2w   = (const float*)d_in[10];
    const float* f2b   = (const float*)d_in[11];
    const int* src = ei;
    const int* tgt = ei + E;

    char* cp = basep;
    f16* packed = (f16*)cp;         cp += packedB;
    f16* nei    = (f16*)cp;         cp += neiB;
    f16* WiA    = (f16*)cp;         cp += wSmall;
    f16* Wh     = (f16*)cp;         cp += wBig;
    f16* WoA    = (f16*)cp;         cp += wSmall;
    f16* WoB    = (f16*)cp;         cp += wBig;
    f16* Wf1    = (f16*)cp;         cp += wBig;
    float* mol  = (float*)cp;       cp += molB;
    f16* h1     = (f16*)cp;         cp += h1B;
    int* rowPtr = (int*)cp;         cp += rpB;
    int* cursor = (int*)cp;         cp += curB;
    int* deg    = (int*)cp;         cp += curB;
    int* csrc   = (int*)cp;         cp += csrcB;
    unsigned* eaPk = (unsigned*)cp; cp += eaB;

    f16* xa_s  = packed;          // slot 0
    f16* hn0_s = packed + 300;    // slot 1 (later atom_h)
    f16* hn1_s = packed + 600;    // slot 2

    const unsigned* packed_u = (const unsigned*)packed;
    unsigned*       nei_u    = (unsigned*)nei;

    const int gAtom = (N + 127) / 128;
    const int gMolG = (B + 127) / 128;
    const int gEdge = (N + APB - 1) / APB;

    // --- CSR build (+ permuted f16 bond features) ---
    zero_i32<<<128, 256, 0, stream>>>(deg, N);
    hist_tgt<<<1024, 256, 0, stream>>>(tgt, deg, E, N);
    scan_deg<<<1, 1024, 0, stream>>>(deg, rowPtr, cursor, N, E);
    scatter_e<<<1024, 256, 0, stream>>>(src, tgt, ea, cursor, csrc, eaPk, E, N);

    // --- weights -> padded f16 ---
    cvt_pad_f16<<<64,  256, 0, stream>>>(WiA, W_i,       300, 147, 133, 144, 320);
    cvt_pad_f16<<<128, 256, 0, stream>>>(Wh,  W_h,       300, 300, 300, 304, 320);
    cvt_pad_f16<<<64,  256, 0, stream>>>(WoA, W_o,       300, 433, 133, 144, 320);
    cvt_pad_f16<<<128, 256, 0, stream>>>(WoB, W_o + 133, 300, 433, 300, 304, 320);
    cvt_pad_f16<<<128, 256, 0, stream>>>(Wf1, f1w,       300, 300, 300, 304, 320);

    // 1. xa = x @ W_i[:, :133]^T -> packed slot0
    gemm_mfma<<<gAtom, 512, 0, stream>>>(x, 133, 0, 133, WiA, 144,
        nullptr, 0, 0, 0, nullptr, 0, nullptr, xa_s, PSTR, N, 0);
    // 2. nei0 = segsum(m0)
    edge_csr<1><<<gEdge, 192, 0, stream>>>(packed_u, rowPtr, csrc, eaPk, W_i,
                                           nei_u, N);
    // 3. hn0 = nei0 @ W_h^T -> packed slot1
    gemm_mfma<<<gAtom, 512, 0, stream>>>(nei, NEIP, 1, NEIP, Wh, 304,
        nullptr, 0, 0, 0, nullptr, 0, nullptr, hn0_s, PSTR, N, 0);
    // 4. nei1 = segsum(m1)
    edge_csr<2><<<gEdge, 192, 0, stream>>>(packed_u, rowPtr, csrc, eaPk, W_i,
                                           nei_u, N);
    // 5. hn1 = nei1 @ W_h^T -> packed slot2
    gemm_mfma<<<gAtom, 512, 0, stream>>>(nei, NEIP, 1, NEIP, Wh, 304,
        nullptr, 0, 0, 0, nullptr, 0, nullptr, hn1_s, PSTR, N, 0);
    // 6. atom_msg = segsum(m2)
    edge_csr<3><<<gEdge, 192, 0, stream>>>(packed_u, rowPtr, csrc, eaPk, W_i,
                                           nei_u, N);
    // 7. atom_h = relu(x @ WoA^T + msg @ WoB^T + b) -> packed slot1
    gemm_mfma<<<gAtom, 512, 0, stream>>>(x, 133, 0, 133, WoA, 144,
        nei, NEIP, 1, NEIP, WoB, 304, W_ob, hn0_s, PSTR, N, 1);
    // 8. mol[b] = segment_sum(atom_h)
    mol_pool<<<B, 256, 0, stream>>>(hn0_s, batch, mol, N);
    // 9. h1 = relu(mol @ ffn1^T + b1)   (MFMA, f16 out)
    gemm_mfma<<<gMolG, 512, 0, stream>>>(mol, 300, 0, 300, Wf1, 304,
        nullptr, 0, 0, 0, nullptr, 0, f1b, h1, NEIP, B, 1);
    // 10. out = h1 @ ffn2^T + b2
    ffn2_k<<<B, 64, 0, stream>>>(h1, f2w, f2b, outp, B);
}

// Round 9
// 901.116 us; speedup vs baseline: 4.3018x; 1.2353x over previous
//
#include <hip/hip_runtime.h>
#include <hip/hip_fp16.h>

#define HID   300
#define NEIP  304            // nei row stride (f16), mult of 16
#define PSTR  900            // packed row stride in f16 (3 slots x 300)
#define APB   4              // atoms per block in edge_csr

typedef _Float16 f16;
typedef f16  f16x2 __attribute__((ext_vector_type(2)));
typedef f16  f16x4 __attribute__((ext_vector_type(4)));
typedef float f32x4 __attribute__((ext_vector_type(4)));

// ---------------------------------------------------------------------------
// helpers
// ---------------------------------------------------------------------------
__device__ __forceinline__ f16x2 u2h(unsigned u) {
    union { unsigned u; f16x2 h; } c; c.u = u; return c.h;
}
__device__ __forceinline__ unsigned pk16(float a, float b) {
    union { f16 h[2]; unsigned u; } c; c.h[0] = (f16)a; c.h[1] = (f16)b;
    return c.u;
}

// ---------------------------------------------------------------------------
__global__ __launch_bounds__(256) void fill_f32(float* __restrict__ p, int n, float v)
{
    int i = blockIdx.x * blockDim.x + threadIdx.x;
    int stride = gridDim.x * blockDim.x;
    for (; i < n; i += stride) p[i] = v;
}

__global__ __launch_bounds__(256) void zero_i32(int* __restrict__ p, int n)
{
    int i = blockIdx.x * blockDim.x + threadIdx.x;
    int stride = gridDim.x * blockDim.x;
    for (; i < n; i += stride) p[i] = 0;
}

// dst [dstRows][kpad] f16 zero-padded; src fp32 [srcRows][ldsrc], kuse cols used
__global__ __launch_bounds__(256) void cvt_pad_f16(
    f16* __restrict__ dst, const float* __restrict__ src,
    int srcRows, int ldsrc, int kuse, int kpad, int dstRows)
{
    int i = blockIdx.x * 256 + threadIdx.x;
    const int total = dstRows * kpad;
    const int st = gridDim.x * 256;
    for (; i < total; i += st) {
        int r = i / kpad, k = i - r * kpad;
        dst[i] = (r < srcRows && k < kuse) ? (f16)src[(size_t)r * ldsrc + k]
                                           : (f16)0.f;
    }
}

// ---------------------------------------------------------------------------
// CSR build: histogram -> hierarchical scan -> scatter (+ ea permute to f16)
// ---------------------------------------------------------------------------
__global__ __launch_bounds__(256) void hist_tgt(
    const int* __restrict__ tgt, int* __restrict__ deg, int E, int N)
{
    int e = blockIdx.x * 256 + threadIdx.x;
    const int st = gridDim.x * 256;
    for (; e < E; e += st) {
        int t = tgt[e];
        t = ((unsigned)t < (unsigned)N) ? t : 0;
        atomicAdd(&deg[t], 1);
    }
}

// phase 1: per-block (1024 elems) tree reduce -> bsum[blockIdx]
__global__ __launch_bounds__(1024) void scan_p1(
    const int* __restrict__ deg, int* __restrict__ bsum, int N)
{
    __shared__ int s[1024];
    const int t = threadIdx.x;
    const int i = blockIdx.x * 1024 + t;
    s[t] = (i < N) ? deg[i] : 0;
    __syncthreads();
#pragma unroll
    for (int off = 512; off > 0; off >>= 1) {
        if (t < off) s[t] += s[t + off];
        __syncthreads();
    }
    if (t == 0) bsum[blockIdx.x] = s[0];
}

// phase 2: single block exclusive-scan of G (<=1024) block sums -> boff
__global__ __launch_bounds__(1024) void scan_p2(
    const int* __restrict__ bsum, int* __restrict__ boff,
    int G, int* __restrict__ rowPtrN, int E)
{
    __shared__ int s[1024];
    const int t = threadIdx.x;
    s[t] = (t < G) ? bsum[t] : 0;
    __syncthreads();
    for (int off = 1; off < 1024; off <<= 1) {
        const int v = (t >= off) ? s[t - off] : 0;
        __syncthreads();
        s[t] += v;
        __syncthreads();
    }
    if (t < G) boff[t] = (t == 0) ? 0 : s[t - 1];
    if (t == 0) *rowPtrN = E;
}

// phase 3: per-block Hillis-Steele scan + boff -> rowPtr, cursor (exclusive)
__global__ __launch_bounds__(1024) void scan_p3(
    const int* __restrict__ deg, const int* __restrict__ boff,
    int* __restrict__ rowPtr, int* __restrict__ cursor, int N)
{
    __shared__ int s[1024];
    const int t = threadIdx.x;
    const int i = blockIdx.x * 1024 + t;
    const int v = (i < N) ? deg[i] : 0;
    s[t] = v;
    __syncthreads();
    for (int off = 1; off < 1024; off <<= 1) {
        const int w = (t >= off) ? s[t - off] : 0;
        __syncthreads();
        s[t] += w;
        __syncthreads();
    }
    if (i < N) {
        const int excl = boff[blockIdx.x] + s[t] - v;
        rowPtr[i] = excl;
        cursor[i] = excl;
    }
}

__global__ __launch_bounds__(256) void scatter_e(
    const int* __restrict__ src, const int* __restrict__ tgt,
    const float* __restrict__ ea,
    int* __restrict__ cursor, int* __restrict__ csrc,
    unsigned* __restrict__ eaPk,    // [E][8] u32 (14 f16 + pad)
    int E, int N)
{
    int e = blockIdx.x * 256 + threadIdx.x;
    const int st = gridDim.x * 256;
    for (; e < E; e += st) {
        int t = tgt[e];
        int s = src[e];
        t = ((unsigned)t < (unsigned)N) ? t : 0;
        s = ((unsigned)s < (unsigned)N) ? s : 0;
        const int p = atomicAdd(&cursor[t], 1);
        csrc[p] = s;
        const float* er = ea + (size_t)e * 14;
        uint4 q0, q1;
        q0.x = pk16(er[0],  er[1]);  q0.y = pk16(er[2],  er[3]);
        q0.z = pk16(er[4],  er[5]);  q0.w = pk16(er[6],  er[7]);
        q1.x = pk16(er[8],  er[9]);  q1.y = pk16(er[10], er[11]);
        q1.z = pk16(er[12], er[13]); q1.w = 0u;
        uint4* dst = (uint4*)(eaPk + (size_t)p * 8);
        dst[0] = q0;
        dst[1] = q1;
    }
}

// ---------------------------------------------------------------------------
// MFMA GEMM (two-phase): C = act( A1@W1^T + A2@W2^T + bias ), 300 out cols.
// A fp32 (guarded, Kuse cols) or f16 (unguarded, padded rows, stride lda).
// W f16 [320][kpad] zero-padded. C: f16, row stride ldc, cols n<300 written.
// Block: 512 thr = 8 waves, BM=128, BK=16, double-buffered LDS.
// Fragments are ds_read BEFORE next-tile staging so MFMA never waits on the
// next tile's global loads (in-order lgkmcnt).
// ---------------------------------------------------------------------------
__global__ __launch_bounds__(512) void gemm_mfma(
    const void* __restrict__ A1, int lda1, int a1f16, int K1use,
    const f16* __restrict__ W1, int kpad1,
    const void* __restrict__ A2, int lda2, int a2f16, int K2use,
    const f16* __restrict__ W2, int kpad2,
    const float* __restrict__ bias,
    f16* __restrict__ C, int ldc,
    int M, int do_relu)
{
    __shared__ f16 As[2][128][20];
    __shared__ f16 Ws[2][320][20];

    const int tid  = threadIdx.x;
    const int bm   = blockIdx.x * 128;
    const int lane = tid & 63;
    const int wv   = tid >> 6;          // 0..7
    const int wrow = (wv >> 2) * 64;    // 0 / 64
    const int wcol = (wv & 3) * 80;     // 0/80/160/240
    const int lm   = lane & 15;
    const int lk   = (lane >> 4) << 2;

    const int n1 = A1 ? (kpad1 >> 4) : 0;
    const int n2 = A2 ? (kpad2 >> 4) : 0;
    const int ntot = n1 + n2;

    f32x4 acc[4][5];
#pragma unroll
    for (int r = 0; r < 4; ++r)
#pragma unroll
        for (int c = 0; c < 5; ++c) acc[r][c] = (f32x4){0.f, 0.f, 0.f, 0.f};

    const int arow = tid >> 2;          // 0..127
    const int akg  = (tid & 3) << 2;    // 0/4/8/12

    auto stage = [&](int s, int b) {
        const void* A; int lda, af16, Kuse, kpad; const f16* W; int k0;
        if (s < n1) { A = A1; lda = lda1; af16 = a1f16; Kuse = K1use;
                      W = W1; kpad = kpad1; k0 = s << 4; }
        else        { A = A2; lda = lda2; af16 = a2f16; Kuse = K2use;
                      W = W2; kpad = kpad2; k0 = (s - n1) << 4; }
        const int gm = bm + arow;
        const int gk = k0 + akg;
        f16x4 va = (f16x4){0, 0, 0, 0};
        if (gm < M) {
            if (af16) {
                va = *(const f16x4*)((const f16*)A + (size_t)gm * lda + gk);
            } else {
                const float* p = (const float*)A + (size_t)gm * lda + gk;
#pragma unroll
                for (int j = 0; j < 4; ++j)
                    va[j] = (gk + j < Kuse) ? (f16)p[j] : (f16)0.f;
            }
        }
        *(f16x4*)&As[b][arow][akg] = va;
#pragma unroll
        for (int it = 0; it < 3; ++it) {
            const int idx = tid + (it << 9);
            if (idx < 1280) {
                const int wr = idx >> 2, kg = (idx & 3) << 2;
                *(f16x4*)&Ws[b][wr][kg] =
                    *(const f16x4*)(W + (size_t)wr * kpad + k0 + kg);
            }
        }
    };

    int b = 0;
    stage(0, 0);
    for (int s = 0; s < ntot; ++s) {
        __syncthreads();
        // 1) fragments of current tile FIRST (ds_read)
        f16x4 af[4], bf[5];
#pragma unroll
        for (int r = 0; r < 4; ++r)
            af[r] = *(const f16x4*)&As[b][wrow + (r << 4) + lm][lk];
#pragma unroll
        for (int c = 0; c < 5; ++c)
            bf[c] = *(const f16x4*)&Ws[b][wcol + (c << 4) + lm][lk];
        // 2) issue next tile staging (global load + ds_write, other buffer)
        if (s + 1 < ntot) stage(s + 1, b ^ 1);
        // 3) MFMA on current fragments
#pragma unroll
        for (int r = 0; r < 4; ++r)
#pragma unroll
            for (int c = 0; c < 5; ++c)
                acc[r][c] = __builtin_amdgcn_mfma_f32_16x16x16f16(
                    af[r], bf[c], acc[r][c], 0, 0, 0);
        b ^= 1;
    }

    // epilogue: C/D frag col = lane&15, row = 4*(lane>>4)+i ; only n<300 stored
#pragma unroll
    for (int r = 0; r < 4; ++r) {
        const int gm0 = bm + wrow + (r << 4) + ((lane >> 4) << 2);
#pragma unroll
        for (int c = 0; c < 5; ++c) {
            const int n = wcol + (c << 4) + lm;
            if (n >= HID) continue;
            const float bi = bias ? bias[n] : 0.f;
#pragma unroll
            for (int i = 0; i < 4; ++i) {
                const int gm = gm0 + i;
                if (gm >= M) continue;
                float v = acc[r][c][i] + bi;
                if (do_relu) v = fmaxf(v, 0.f);
                C[(size_t)gm * ldc + n] = (f16)v;
            }
        }
    }
}

// ---------------------------------------------------------------------------
// edge_csr: per target atom, accumulate messages of incoming edges in fp32
// registers, store one coalesced row. Packed-f16 math, no atomics.
//   m = relu(packed[s,0] + eaPk[j] @ Wb^T); relu(+packed[s,1]); relu(+packed[s,2])
// Block handles APB atoms; thread p = channel pair (2p, 2p+1).
// ---------------------------------------------------------------------------
template <int NSLOTS>
__global__ __launch_bounds__(192) void edge_csr(
    const unsigned* __restrict__ packed,  // [N][450] u32 pairs (slots +0/+150/+300)
    const int* __restrict__ rowPtr,
    const int* __restrict__ csrc,
    const unsigned* __restrict__ eaPk,    // [E][8] u32 (14 f16)
    const float* __restrict__ Wi,         // [300,147] fp32 (bond cols 133..146)
    unsigned* __restrict__ out,           // nei [N][152] u32 pairs
    int N)
{
    const int p = threadIdx.x;
    f16x2 wpk[14];
    if (p < 150) {
#pragma unroll
        for (int k = 0; k < 14; ++k)
            wpk[k] = (f16x2){(f16)Wi[(2 * p) * 147 + 133 + k],
                             (f16)Wi[(2 * p + 1) * 147 + 133 + k]};
    }
    const f16x2 zero2 = (f16x2){(f16)0.f, (f16)0.f};

    const int a0 = blockIdx.x * APB;
    const int a1 = min(a0 + APB, N);
    for (int a = a0; a < a1; ++a) {
        const int beg = rowPtr[a];
        const int end = rowPtr[a + 1];
        float acc0 = 0.f, acc1 = 0.f;
        if (p < 150) {
#pragma unroll 2
            for (int j = beg; j < end; ++j) {
                const int s = csrc[j];
                const unsigned* row = packed + (size_t)s * (PSTR / 2);
                const unsigned u0 = row[p];
                unsigned u1 = 0, u2 = 0;
                if (NSLOTS > 1) u1 = row[p + 150];
                if (NSLOTS > 2) u2 = row[p + 300];
                const unsigned* eq = eaPk + (size_t)j * 8;
                f16x2 ebA = zero2, ebB = zero2;
#pragma unroll
                for (int k = 0; k < 7; ++k) {
                    const f16x2 e2 = u2h(eq[k]);
                    ebA += (f16x2){e2.x, e2.x} * wpk[2 * k];
                    ebB += (f16x2){e2.y, e2.y} * wpk[2 * k + 1];
                }
                f16x2 m = __builtin_elementwise_max(u2h(u0) + (ebA + ebB), zero2);
                if (NSLOTS > 1) m = __builtin_elementwise_max(m + u2h(u1), zero2);
                if (NSLOTS > 2) m = __builtin_elementwise_max(m + u2h(u2), zero2);
                acc0 += (float)m.x;
                acc1 += (float)m.y;
            }
        }
        if (p < NEIP / 2)
            out[(size_t)a * (NEIP / 2) + p] = (p < 150) ? pk16(acc0, acc1) : 0u;
    }
}

// ---------------------------------------------------------------------------
// mol_pool: mol[b,:300] = sum of atom_h rows (f16, stride PSTR) with batch==b
// ---------------------------------------------------------------------------
__global__ __launch_bounds__(256) void mol_pool(
    const f16* __restrict__ ah,       // packed slot1: [N] rows stride 900
    const int* __restrict__ batch,    // [N], sorted
    float* __restrict__ mol,          // [B,300]
    int N)
{
    const int b = blockIdx.x;
    int lo = 0, hi = N;
    while (lo < hi) { int mid = (lo + hi) >> 1; if (batch[mid] < b) lo = mid + 1; else hi = mid; }
    const int start = lo;
    hi = N;
    while (lo < hi) { int mid = (lo + hi) >> 1; if (batch[mid] < b + 1) lo = mid + 1; else hi = mid; }
    const int end = lo;

    for (int h = threadIdx.x; h < HID; h += 256) {
        float s = 0.f;
        for (int a = start; a < end; ++a) s += (float)ah[(size_t)a * PSTR + h];
        mol[(size_t)b * HID + h] = s;
    }
}

// ---------------------------------------------------------------------------
__global__ __launch_bounds__(64) void ffn2_k(
    const f16* __restrict__ h1,       // [B][304] f16
    const float* __restrict__ w2,     // [300]
    const float* __restrict__ b2, float* __restrict__ out, int B)
{
    const int b = blockIdx.x;
    float s = 0.f;
    for (int k = threadIdx.x; k < HID; k += 64)
        s += (float)h1[(size_t)b * NEIP + k] * w2[k];
#pragma unroll
    for (int off = 32; off > 0; off >>= 1) s += __shfl_down(s, off);
    if (threadIdx.x == 0) out[b] = s + b2[0];
}

// ---------------------------------------------------------------------------
extern "C" void kernel_launch(void* const* d_in, const int* in_sizes, int n_in,
                              void* d_out, int out_size, void* d_ws, size_t ws_size,
                              hipStream_t stream)
{
    float* outp = (float*)d_out;
    const int fillBlocks = (out_size + 255) / 256;

    if (n_in < 12) {
        fill_f32<<<fillBlocks, 256, 0, stream>>>(outp, out_size, 2.0e6f + n_in);
        return;
    }

    const int N = in_sizes[0] / 133;   // atoms
    const int E = in_sizes[1] / 2;     // edges
    const int B = out_size;            // molecules

    const long long expect[12] = {
        (long long)N * 133, (long long)E * 2, (long long)E * 14, N,
        300LL * 147, 300LL * 300, 300LL * 433, 300,
        300LL * 300, 300, 300, 1 };
    for (int i = 0; i < 12; ++i) {
        if ((long long)in_sizes[i] != expect[i]) {
            fill_f32<<<fillBlocks, 256, 0, stream>>>(outp, out_size,
                                                     3.0e6f + 1.0e4f * i);
            return;
        }
    }

    const int G = (N + 1023) / 1024;   // scan blocks (<=1024 assumed; N=100K -> 98)
    if (G > 1024) {
        fill_f32<<<fillBlocks, 256, 0, stream>>>(outp, out_size, 4.0e6f);
        return;
    }

    // ---- workspace layout ---------------------------------------------------
    // packed f16 [N][900] (slot0=xa, slot1=hn0/atom_h, slot2=hn1)    180.0 MB
    // nei    f16 [N][304]                                             60.8 MB
    // weights WiA[320][144] Wh[320][304] WoA[320][144] WoB[320][304]
    //         Wf1[320][304]                                            0.77 MB
    // mol f32 [B,300]  h1 f16 [B,304]                                  7.4 MB
    // rowPtr[N+1] cursor[N] deg[N] csrc[E] eaPk[E][8]u32 bsum/boff    16.0 MB
    char* basep = (char*)d_ws;
    auto align16 = [](size_t v) { return (v + 15) & ~(size_t)15; };
    const size_t packedB = align16((size_t)N * PSTR * sizeof(f16));
    const size_t neiB    = align16((size_t)N * NEIP * sizeof(f16));
    const size_t wSmall  = align16(320 * 144 * sizeof(f16));
    const size_t wBig    = align16(320 * 304 * sizeof(f16));
    const size_t molB    = align16((size_t)B * HID * sizeof(float));
    const size_t h1B     = align16((size_t)B * NEIP * sizeof(f16));
    const size_t rpB     = align16((size_t)(N + 1) * sizeof(int));
    const size_t curB    = align16((size_t)N * sizeof(int));
    const size_t csrcB   = align16((size_t)E * sizeof(int));
    const size_t eaB     = align16((size_t)E * 8 * sizeof(unsigned));
    const size_t bsB     = align16(1024 * sizeof(int));
    const size_t need = packedB + neiB + 2 * wSmall + 3 * wBig
                      + molB + h1B + rpB + 2 * curB + csrcB + eaB + 2 * bsB;

    if (ws_size < need) {
        fill_f32<<<fillBlocks, 256, 0, stream>>>(outp, out_size,
                                                 (float)(ws_size >> 20));
        return;
    }

    const float* x     = (const float*)d_in[0];
    const int*   ei    = (const int*)d_in[1];
    const float* ea    = (const float*)d_in[2];
    const int*   batch = (const int*)d_in[3];
    const float* W_i   = (const float*)d_in[4];
    const float* W_h   = (const float*)d_in[5];
    const float* W_o   = (const float*)d_in[6];
    const float* W_ob  = (const float*)d_in[7];
    const float* f1w   = (const float*)d_in[8];
    const float* f1b   = (const float*)d_in[9];
    const float* f2w   = (const float*)d_in[10];
    const float* f2b   = (const float*)d_in[11];
    const int* src = ei;
    const int* tgt = ei + E;

    char* cp = basep;
    f16* packed = (f16*)cp;         cp += packedB;
    f16* nei    = (f16*)cp;         cp += neiB;
    f16* WiA    = (f16*)cp;         cp += wSmall;
    f16* Wh     = (f16*)cp;         cp += wBig;
    f16* WoA    = (f16*)cp;         cp += wSmall;
    f16* WoB    = (f16*)cp;         cp += wBig;
    f16* Wf1    = (f16*)cp;         cp += wBig;
    float* mol  = (float*)cp;       cp += molB;
    f16* h1     = (f16*)cp;         cp += h1B;
    int* rowPtr = (int*)cp;         cp += rpB;
    int* cursor = (int*)cp;         cp += curB;
    int* deg    = (int*)cp;         cp += curB;
    int* csrc   = (int*)cp;         cp += csrcB;
    unsigned* eaPk = (unsigned*)cp; cp += eaB;
    int* bsum   = (int*)cp;         cp += bsB;
    int* boff   = (int*)cp;         cp += bsB;

    f16* xa_s  = packed;          // slot 0
    f16* hn0_s = packed + 300;    // slot 1 (later atom_h)
    f16* hn1_s = packed + 600;    // slot 2

    const unsigned* packed_u = (const unsigned*)packed;
    unsigned*       nei_u    = (unsigned*)nei;

    const int gAtom = (N + 127) / 128;
    const int gMolG = (B + 127) / 128;
    const int gEdge = (N + APB - 1) / APB;

    // --- CSR build (+ permuted f16 bond features) ---
    zero_i32<<<128, 256, 0, stream>>>(deg, N);
    hist_tgt<<<1024, 256, 0, stream>>>(tgt, deg, E, N);
    scan_p1<<<G, 1024, 0, stream>>>(deg, bsum, N);
    scan_p2<<<1, 1024, 0, stream>>>(bsum, boff, G, rowPtr + N, E);
    scan_p3<<<G, 1024, 0, stream>>>(deg, boff, rowPtr, cursor, N);
    scatter_e<<<1024, 256, 0, stream>>>(src, tgt, ea, cursor, csrc, eaPk, E, N);

    // --- weights -> padded f16 ---
    cvt_pad_f16<<<64,  256, 0, stream>>>(WiA, W_i,       300, 147, 133, 144, 320);
    cvt_pad_f16<<<128, 256, 0, stream>>>(Wh,  W_h,       300, 300, 300, 304, 320);
    cvt_pad_f16<<<64,  256, 0, stream>>>(WoA, W_o,       300, 433, 133, 144, 320);
    cvt_pad_f16<<<128, 256, 0, stream>>>(WoB, W_o + 133, 300, 433, 300, 304, 320);
    cvt_pad_f16<<<128, 256, 0, stream>>>(Wf1, f1w,       300, 300, 300, 304, 320);

    // 1. xa = x @ W_i[:, :133]^T -> packed slot0
    gemm_mfma<<<gAtom, 512, 0, stream>>>(x, 133, 0, 133, WiA, 144,
        nullptr, 0, 0, 0, nullptr, 0, nullptr, xa_s, PSTR, N, 0);
    // 2. nei0 = segsum(m0)
    edge_csr<1><<<gEdge, 192, 0, stream>>>(packed_u, rowPtr, csrc, eaPk, W_i,
                                           nei_u, N);
    // 3. hn0 = nei0 @ W_h^T -> packed slot1
    gemm_mfma<<<gAtom, 512, 0, stream>>>(nei, NEIP, 1, NEIP, Wh, 304,
        nullptr, 0, 0, 0, nullptr, 0, nullptr, hn0_s, PSTR, N, 0);
    // 4. nei1 = segsum(m1)
    edge_csr<2><<<gEdge, 192, 0, stream>>>(packed_u, rowPtr, csrc, eaPk, W_i,
                                           nei_u, N);
    // 5. hn1 = nei1 @ W_h^T -> packed slot2
    gemm_mfma<<<gAtom, 512, 0, stream>>>(nei, NEIP, 1, NEIP, Wh, 304,
        nullptr, 0, 0, 0, nullptr, 0, nullptr, hn1_s, PSTR, N, 0);
    // 6. atom_msg = segsum(m2)
    edge_csr<3><<<gEdge, 192, 0, stream>>>(packed_u, rowPtr, csrc, eaPk, W_i,
                                           nei_u, N);
    // 7. atom_h = relu(x @ WoA^T + msg @ WoB^T + b) -> packed slot1
    gemm_mfma<<<gAtom, 512, 0, stream>>>(x, 133, 0, 133, WoA, 144,
        nei, NEIP, 1, NEIP, WoB, 304, W_ob, hn0_s, PSTR, N, 1);
    // 8. mol[b] = segment_sum(atom_h)
    mol_pool<<<B, 256, 0, stream>>>(hn0_s, batch, mol, N);
    // 9. h1 = relu(mol @ ffn1^T + b1)   (MFMA, f16 out)
    gemm_mfma<<<gMolG, 512, 0, stream>>>(mol, 300, 0, 300, Wf1, 304,
        nullptr, 0, 0, 0, nullptr, 0, f1b, h1, NEIP, B, 1);
    // 10. out = h1 @ ffn2^T + b2
    ffn2_k<<<B, 64, 0, stream>>>(h1, f2w, f2b, outp, B);
}